// Round 1
// baseline (1225.174 us; speedup 1.0000x reference)
//
#include <hip/hip_runtime.h>
#include <hip/hip_bf16.h>

typedef __bf16 bf16x8 __attribute__((ext_vector_type(8)));
typedef float f32x4 __attribute__((ext_vector_type(4)));

// B=2, T=2048, d=768, h=8
#define SCALE 0.03608439182435161f   // 1/sqrt(768)
#define NEGINF (-1e30f)

static __device__ __forceinline__ ushort f2bf(float f) {
    union { float f; unsigned u; } v; v.f = f;
    unsigned r = (v.u + 0x7fff + ((v.u >> 16) & 1)) >> 16;  // RTE
    return (ushort)r;
}
static __device__ __forceinline__ float bf2f(ushort u) {
    union { unsigned u; float f; } v; v.u = ((unsigned)u) << 16;
    return v.f;
}

// ---------------- f32 -> bf16 convert (x) ----------------
__global__ void k_convx(const float* __restrict__ x, ushort* __restrict__ xb, int n4) {
    int i = blockIdx.x * blockDim.x + threadIdx.x;
    if (i >= n4) return;
    float4 v = ((const float4*)x)[i];
    ushort4 o; o.x = f2bf(v.x); o.y = f2bf(v.y); o.z = f2bf(v.z); o.w = f2bf(v.w);
    ((ushort4*)xb)[i] = o;
}

// ---------------- f32 [R][C] -> bf16 [C][R] transpose-convert ----------------
__global__ void k_tconv(const float* __restrict__ in, ushort* __restrict__ out, int R, int C) {
    __shared__ float ts[32][33];
    int r0 = blockIdx.x * 32, c0 = blockIdx.y * 32;
    int lr = threadIdx.x >> 5, lc = threadIdx.x & 31;
#pragma unroll
    for (int i = 0; i < 4; i++) ts[lr + i * 8][lc] = in[(r0 + lr + i * 8) * C + c0 + lc];
    __syncthreads();
#pragma unroll
    for (int i = 0; i < 4; i++) out[(c0 + lr + i * 8) * R + r0 + lc] = f2bf(ts[lc][lr + i * 8]);
}

// ---------------- bf16 GEMM: C[M][N] = A[M][768] * Bt[N][768]^T ----------------
// EPI 0: write Q[b][h][t][dd]  (row = b*2048+t over M=4096, col = h*768+dd over N=6144)
// EPI 1: write valT[b][h][dd][t] (row = h*768+dd over M=6144, col = b*2048+t over N=4096)
template <int EPI>
__global__ __launch_bounds__(256) void k_gemm(const ushort* __restrict__ A,
                                              const ushort* __restrict__ Bt,
                                              ushort* __restrict__ out) {
    __shared__ ushort As[128 * 40];
    __shared__ ushort Bs[128 * 40];
    const int m0 = blockIdx.x * 128, n0 = blockIdx.y * 128;
    const int tid = threadIdx.x, lane = tid & 63, wid = tid >> 6;
    const int wm = (wid >> 1) * 64, wn = (wid & 1) * 64;
    f32x4 acc[4][4] = {};

    for (int kt = 0; kt < 768; kt += 32) {
#pragma unroll
        for (int i = 0; i < 2; i++) {
            int c = tid + i * 256;
            int row = c >> 2, kc = (c & 3) * 8;
            uint4 va = *(const uint4*)&A[(m0 + row) * 768 + kt + kc];
            *(uint4*)&As[row * 40 + kc] = va;
            uint4 vb = *(const uint4*)&Bt[(n0 + row) * 768 + kt + kc];
            *(uint4*)&Bs[row * 40 + kc] = vb;
        }
        __syncthreads();
        bf16x8 af[4], bfr[4];
#pragma unroll
        for (int m = 0; m < 4; m++)
            af[m] = *(const bf16x8*)&As[(wm + m * 16 + (lane & 15)) * 40 + (lane >> 4) * 8];
#pragma unroll
        for (int n = 0; n < 4; n++)
            bfr[n] = *(const bf16x8*)&Bs[(wn + n * 16 + (lane & 15)) * 40 + (lane >> 4) * 8];
#pragma unroll
        for (int m = 0; m < 4; m++)
#pragma unroll
            for (int n = 0; n < 4; n++)
                acc[m][n] = __builtin_amdgcn_mfma_f32_16x16x32_bf16(af[m], bfr[n], acc[m][n], 0, 0, 0);
        __syncthreads();
    }

#pragma unroll
    for (int m = 0; m < 4; m++) {
#pragma unroll
        for (int n = 0; n < 4; n++) {
#pragma unroll
            for (int r = 0; r < 4; r++) {
                int row = m0 + wm + m * 16 + (lane >> 4) * 4 + r;
                int col = n0 + wn + n * 16 + (lane & 15);
                float v = acc[m][n][r];
                int idx;
                if (EPI == 0) {
                    int b = row >> 11, t = row & 2047;
                    int hh = col / 768, dd = col - hh * 768;
                    idx = ((b * 8 + hh) * 2048 + t) * 768 + dd;
                } else {
                    int hh = row / 768, dd = row - hh * 768;
                    int b = col >> 11, t = col & 2047;
                    idx = ((b * 8 + hh) * 768 + dd) * 2048 + t;
                }
                out[idx] = f2bf(v);
            }
        }
    }
}

// ---------------- RoPE on Q in-place (bf16, layout [b][h][t][768]) ----------------
__global__ void k_ropeq(ushort* __restrict__ Q, const int* __restrict__ pos, int nrows) {
    int i = blockIdx.x * blockDim.x + threadIdx.x;
    int row = i / 96, j4 = (i % 96) * 4;
    if (row >= nrows) return;
    float p = (float)pos[row & 2047];
    ushort4 u1 = *(ushort4*)&Q[row * 768 + j4];
    ushort4 u2 = *(ushort4*)&Q[row * 768 + 384 + j4];
    ushort4 o1, o2;
#pragma unroll
    for (int k = 0; k < 4; k++) {
        float inv = exp2f(-(float)(j4 + k) * (13.287712379549449f / 384.0f));
        float ang = p * inv;
        float s, c; sincosf(ang, &s, &c);
        float x1 = bf2f(((ushort*)&u1)[k]), x2 = bf2f(((ushort*)&u2)[k]);
        ((ushort*)&o1)[k] = f2bf(x1 * c - x2 * s);
        ((ushort*)&o2)[k] = f2bf(x1 * s + x2 * c);
    }
    *(ushort4*)&Q[row * 768 + j4] = o1;
    *(ushort4*)&Q[row * 768 + 384 + j4] = o2;
}

// ---------------- RoPE(x) -> Kr bf16 (layout [b][t][768]) ----------------
__global__ void k_ropek(const float* __restrict__ x, ushort* __restrict__ Kr,
                        const int* __restrict__ pos, int nrows) {
    int i = blockIdx.x * blockDim.x + threadIdx.x;
    int row = i / 96, j4 = (i % 96) * 4;
    if (row >= nrows) return;
    float p = (float)pos[row & 2047];
    float4 x1 = *(const float4*)&x[row * 768 + j4];
    float4 x2 = *(const float4*)&x[row * 768 + 384 + j4];
    ushort4 o1, o2;
    float a1[4] = {x1.x, x1.y, x1.z, x1.w};
    float a2[4] = {x2.x, x2.y, x2.z, x2.w};
#pragma unroll
    for (int k = 0; k < 4; k++) {
        float inv = exp2f(-(float)(j4 + k) * (13.287712379549449f / 384.0f));
        float ang = p * inv;
        float s, c; sincosf(ang, &s, &c);
        ((ushort*)&o1)[k] = f2bf(a1[k] * c - a2[k] * s);
        ((ushort*)&o2)[k] = f2bf(a1[k] * s + a2[k] * c);
    }
    *(ushort4*)&Kr[row * 768 + j4] = o1;
    *(ushort4*)&Kr[row * 768 + 384 + j4] = o2;
}

// ---------------- Flash attention, QBLK=32, KBLK=64, 8 waves ----------------
// Qr: [b][h][t][768] bf16 (roped); Kr: [b][t][768] bf16 (roped, head-shared);
// valT: [b][h][dd][t] bf16. out: f32 [b][t][768], accumulated over h via atomicAdd.
__global__ __launch_bounds__(512) void k_attn(const ushort* __restrict__ Qr,
                                              const ushort* __restrict__ Kr,
                                              const ushort* __restrict__ valT,
                                              float* __restrict__ out) {
    __shared__ ushort Qs[32 * 768];     // swizzled rows, stride 1536B
    __shared__ ushort KVs[64 * 768];    // K: [64][768]; later V: [768][64]
    __shared__ float S_lds[32][68];
    __shared__ ushort P_lds[32 * 72];
    __shared__ float m_s[32], l_s[32], resc[32];

    const int qb = blockIdx.x, hh = blockIdx.y, b = blockIdx.z;
    const int bh = b * 8 + hh;
    const int tid = threadIdx.x, lane = tid & 63, wid = tid >> 6;

    // stage Q tile (32 x 768), XOR-swizzled
    for (int c = tid; c < 3072; c += 512) {
        int row = c / 96, col = (c % 96) * 8;
        uint4 v = *(const uint4*)&Qr[(bh * 2048 + qb * 32 + row) * 768 + col];
        int addr = (row * 1536 + col * 2) ^ ((row & 7) << 4);
        *(uint4*)((char*)Qs + addr) = v;
    }
    if (tid < 32) { m_s[tid] = NEGINF; l_s[tid] = 0.f; }

    f32x4 oacc[2][6] = {};
    const int nkb = ((qb * 32 + 31) >> 6) + 1;
    const int mi = (wid >> 2) * 16, ni = (wid & 3) * 16;

    for (int kb = 0; kb < nkb; kb++) {
        __syncthreads();  // KVs free (prev PV done); also covers Q staging on kb==0
        // stage K tile (64 x 768), swizzled
        for (int c = tid; c < 6144; c += 512) {
            int row = c / 96, col = (c % 96) * 8;
            uint4 v = *(const uint4*)&Kr[(b * 2048 + kb * 64 + row) * 768 + col];
            int addr = (row * 1536 + col * 2) ^ ((row & 7) << 4);
            *(uint4*)((char*)KVs + addr) = v;
        }
        __syncthreads();

        // S = Q * K^T  (each wave one 16x16 tile of the 32x64 S)
        f32x4 s = {};
#pragma unroll 4
        for (int dc = 0; dc < 24; dc++) {
            int ko = dc * 32 + (lane >> 4) * 8;
            int ra = mi + (lane & 15);
            bf16x8 a = *(const bf16x8*)((char*)Qs + ((ra * 1536 + ko * 2) ^ ((ra & 7) << 4)));
            int rb = ni + (lane & 15);
            bf16x8 bb = *(const bf16x8*)((char*)KVs + ((rb * 1536 + ko * 2) ^ ((rb & 7) << 4)));
            s = __builtin_amdgcn_mfma_f32_16x16x32_bf16(a, bb, s, 0, 0, 0);
        }
#pragma unroll
        for (int r = 0; r < 4; r++)
            S_lds[mi + (lane >> 4) * 4 + r][ni + (lane & 15)] = s[r];
        __syncthreads();

        // stage V tile (768 x 64, from valT rows) early — loads overlap softmax VALU
        for (int c = tid; c < 6144; c += 512) {
            int row = c >> 3, col = (c & 7) * 8;
            uint4 v = *(const uint4*)&valT[(bh * 768 + row) * 2048 + kb * 64 + col];
            int addr = (row * 128 + col * 2) ^ ((row & 7) << 4);
            *(uint4*)((char*)KVs + addr) = v;
        }

        // online softmax: one 16-lane group per row
        {
            int r = tid >> 4, lg = tid & 15;
            int qg = qb * 32 + r;
            float sv[4]; float pmax = NEGINF;
#pragma unroll
            for (int i2 = 0; i2 < 4; i2++) {
                int c = lg + i2 * 16;
                float v = S_lds[r][c] * SCALE;
                if (kb * 64 + c > qg) v = NEGINF;
                sv[i2] = v; pmax = fmaxf(pmax, v);
            }
#pragma unroll
            for (int m2 = 1; m2 < 16; m2 <<= 1) pmax = fmaxf(pmax, __shfl_xor(pmax, m2));
            float m_old = m_s[r];
            float m_new = fmaxf(m_old, pmax);
            float psum = 0.f;
#pragma unroll
            for (int i2 = 0; i2 < 4; i2++) {
                float pp = __expf(sv[i2] - m_new);
                psum += pp;
                P_lds[r * 72 + lg + i2 * 16] = f2bf(pp);
            }
#pragma unroll
            for (int m2 = 1; m2 < 16; m2 <<= 1) psum += __shfl_xor(psum, m2);
            if (lg == 0) {
                float fac = __expf(m_old - m_new);
                l_s[r] = l_s[r] * fac + psum;
                m_s[r] = m_new;
                resc[r] = fac;
            }
        }
        __syncthreads();

        // rescale O, then O += P * V   (wave owns 96 output cols)
#pragma unroll
        for (int m2 = 0; m2 < 2; m2++) {
#pragma unroll
            for (int r = 0; r < 4; r++) {
                float f = resc[m2 * 16 + (lane >> 4) * 4 + r];
#pragma unroll
                for (int n2 = 0; n2 < 6; n2++) oacc[m2][n2][r] *= f;
            }
        }
#pragma unroll
        for (int kc = 0; kc < 2; kc++) {
            bf16x8 pa[2];
#pragma unroll
            for (int m2 = 0; m2 < 2; m2++)
                pa[m2] = *(const bf16x8*)&P_lds[(m2 * 16 + (lane & 15)) * 72 + kc * 32 + (lane >> 4) * 8];
#pragma unroll
            for (int n2 = 0; n2 < 6; n2++) {
                int vr = wid * 96 + n2 * 16 + (lane & 15);
                bf16x8 vb = *(const bf16x8*)((char*)KVs +
                              ((vr * 128 + (kc * 32 + (lane >> 4) * 8) * 2) ^ ((vr & 7) << 4)));
#pragma unroll
                for (int m2 = 0; m2 < 2; m2++)
                    oacc[m2][n2] = __builtin_amdgcn_mfma_f32_16x16x32_bf16(pa[m2], vb, oacc[m2][n2], 0, 0, 0);
            }
        }
    }
    __syncthreads();

    // epilogue: divide by l, accumulate over heads
#pragma unroll
    for (int m2 = 0; m2 < 2; m2++) {
#pragma unroll
        for (int r = 0; r < 4; r++) {
            int rl = m2 * 16 + (lane >> 4) * 4 + r;
            float inv = 1.0f / l_s[rl];
            int gq = qb * 32 + rl;
#pragma unroll
            for (int n2 = 0; n2 < 6; n2++) {
                int gd = wid * 96 + n2 * 16 + (lane & 15);
                atomicAdd(&out[(b * 2048 + gq) * 768 + gd], oacc[m2][n2][r] * inv);
            }
        }
    }
}

extern "C" void kernel_launch(void* const* d_in, const int* in_sizes, int n_in,
                              void* d_out, int out_size, void* d_ws, size_t ws_size,
                              hipStream_t stream) {
    const float* x = (const float*)d_in[0];
    const float* M = (const float*)d_in[1];
    const float* V = (const float*)d_in[2];
    const int* pos = (const int*)d_in[3];
    float* out = (float*)d_out;
    char* ws = (char*)d_ws;

    // workspace layout (bytes)
    ushort* xb   = (ushort*)(ws);                 //  6,291,456  x bf16 [4096][768]
    ushort* Mt   = (ushort*)(ws + 6291456);       //  9,437,184  M^T bf16 [6144][768]
    ushort* Vt   = (ushort*)(ws + 15728640);      //  9,437,184  V^T bf16 [6144][768]
    ushort* Qr   = (ushort*)(ws + 25165824);      // 50,331,648  Q bf16 [b][h][t][768]
    ushort* valT = (ushort*)(ws + 75497472);      // 50,331,648  val^T bf16 [b][h][dd][t]
    ushort* Kr   = (ushort*)(ws + 125829120);     //  6,291,456  K bf16 [b][t][768]

    hipMemsetAsync(d_out, 0, (size_t)out_size * 4, stream);
    k_convx<<<3072, 256, 0, stream>>>(x, xb, 786432);
    k_tconv<<<dim3(24, 192), 256, 0, stream>>>(M, Mt, 768, 6144);
    k_tconv<<<dim3(24, 192), 256, 0, stream>>>(V, Vt, 768, 6144);
    k_gemm<0><<<dim3(32, 48), 256, 0, stream>>>(xb, Mt, Qr);
    k_gemm<1><<<dim3(48, 32), 256, 0, stream>>>(Vt, xb, valT);
    k_ropeq<<<12288, 256, 0, stream>>>(Qr, pos, 32768);
    k_ropek<<<1536, 256, 0, stream>>>(x, Kr, pos, 4096);
    k_attn<<<dim3(64, 8, 2), 512, 0, stream>>>(Qr, Kr, valT, out);
}

// Round 2
// 448.696 us; speedup vs baseline: 2.7305x; 2.7305x over previous
//
#include <hip/hip_runtime.h>
#include <hip/hip_bf16.h>

typedef __bf16 bf16x8 __attribute__((ext_vector_type(8)));
typedef float f32x4 __attribute__((ext_vector_type(4)));

// B=2, T=2048, d=768, h=8
#define SCALE 0.03608439182435161f   // 1/sqrt(768)
#define NEGINF (-1e30f)

static __device__ __forceinline__ ushort f2bf(float f) {
    union { float f; unsigned u; } v; v.f = f;
    unsigned r = (v.u + 0x7fff + ((v.u >> 16) & 1)) >> 16;  // RTE
    return (ushort)r;
}
static __device__ __forceinline__ float bf2f(ushort u) {
    union { unsigned u; float f; } v; v.u = ((unsigned)u) << 16;
    return v.f;
}

// async 16B global -> LDS (dest: wave-uniform base + lane*16)
static __device__ __forceinline__ void gload16(const void* g, void* lds) {
    __builtin_amdgcn_global_load_lds((const __attribute__((address_space(1))) void*)g,
                                     (__attribute__((address_space(3))) void*)lds, 16, 0, 0);
}

// ---------------- f32 -> bf16 convert (x) ----------------
__global__ void k_convx(const float* __restrict__ x, ushort* __restrict__ xb, int n4) {
    int i = blockIdx.x * blockDim.x + threadIdx.x;
    if (i >= n4) return;
    float4 v = ((const float4*)x)[i];
    ushort4 o; o.x = f2bf(v.x); o.y = f2bf(v.y); o.z = f2bf(v.z); o.w = f2bf(v.w);
    ((ushort4*)xb)[i] = o;
}

// ---------------- f32 [R][C] -> bf16 [C][R] transpose-convert ----------------
__global__ void k_tconv(const float* __restrict__ in, ushort* __restrict__ out, int R, int C) {
    __shared__ float ts[32][33];
    int r0 = blockIdx.x * 32, c0 = blockIdx.y * 32;
    int lr = threadIdx.x >> 5, lc = threadIdx.x & 31;
#pragma unroll
    for (int i = 0; i < 4; i++) ts[lr + i * 8][lc] = in[(r0 + lr + i * 8) * C + c0 + lc];
    __syncthreads();
#pragma unroll
    for (int i = 0; i < 4; i++) out[(c0 + lr + i * 8) * R + r0 + lc] = f2bf(ts[lc][lr + i * 8]);
}

// ---------------- bf16 GEMM: C[M][N] = A[M][768] * Bt[N][768]^T ----------------
template <int EPI>
__global__ __launch_bounds__(256) void k_gemm(const ushort* __restrict__ A,
                                              const ushort* __restrict__ Bt,
                                              ushort* __restrict__ out) {
    __shared__ ushort As[128 * 40];
    __shared__ ushort Bs[128 * 40];
    const int m0 = blockIdx.x * 128, n0 = blockIdx.y * 128;
    const int tid = threadIdx.x, lane = tid & 63, wid = tid >> 6;
    const int wm = (wid >> 1) * 64, wn = (wid & 1) * 64;
    f32x4 acc[4][4] = {};

    for (int kt = 0; kt < 768; kt += 32) {
#pragma unroll
        for (int i = 0; i < 2; i++) {
            int c = tid + i * 256;
            int row = c >> 2, kc = (c & 3) * 8;
            uint4 va = *(const uint4*)&A[(m0 + row) * 768 + kt + kc];
            *(uint4*)&As[row * 40 + kc] = va;
            uint4 vb = *(const uint4*)&Bt[(n0 + row) * 768 + kt + kc];
            *(uint4*)&Bs[row * 40 + kc] = vb;
        }
        __syncthreads();
        bf16x8 af[4], bfr[4];
#pragma unroll
        for (int m = 0; m < 4; m++)
            af[m] = *(const bf16x8*)&As[(wm + m * 16 + (lane & 15)) * 40 + (lane >> 4) * 8];
#pragma unroll
        for (int n = 0; n < 4; n++)
            bfr[n] = *(const bf16x8*)&Bs[(wn + n * 16 + (lane & 15)) * 40 + (lane >> 4) * 8];
#pragma unroll
        for (int m = 0; m < 4; m++)
#pragma unroll
            for (int n = 0; n < 4; n++)
                acc[m][n] = __builtin_amdgcn_mfma_f32_16x16x32_bf16(af[m], bfr[n], acc[m][n], 0, 0, 0);
        __syncthreads();
    }

#pragma unroll
    for (int m = 0; m < 4; m++) {
#pragma unroll
        for (int n = 0; n < 4; n++) {
#pragma unroll
            for (int r = 0; r < 4; r++) {
                int row = m0 + wm + m * 16 + (lane >> 4) * 4 + r;
                int col = n0 + wn + n * 16 + (lane & 15);
                float v = acc[m][n][r];
                int idx;
                if (EPI == 0) {
                    int b = row >> 11, t = row & 2047;
                    int hh = col / 768, dd = col - hh * 768;
                    idx = ((b * 8 + hh) * 2048 + t) * 768 + dd;
                } else {
                    int hh = row / 768, dd = row - hh * 768;
                    int b = col >> 11, t = col & 2047;
                    idx = ((b * 8 + hh) * 768 + dd) * 2048 + t;
                }
                out[idx] = f2bf(v);
            }
        }
    }
}

// ---------------- RoPE on Q in-place (bf16, layout [b][h][t][768]) ----------------
__global__ void k_ropeq(ushort* __restrict__ Q, const int* __restrict__ pos, int nrows) {
    int i = blockIdx.x * blockDim.x + threadIdx.x;
    int row = i / 96, j4 = (i % 96) * 4;
    if (row >= nrows) return;
    float p = (float)pos[row & 2047];
    ushort4 u1 = *(ushort4*)&Q[row * 768 + j4];
    ushort4 u2 = *(ushort4*)&Q[row * 768 + 384 + j4];
    ushort4 o1, o2;
#pragma unroll
    for (int k = 0; k < 4; k++) {
        float inv = exp2f(-(float)(j4 + k) * (13.287712379549449f / 384.0f));
        float ang = p * inv;
        float s, c; sincosf(ang, &s, &c);
        float x1 = bf2f(((ushort*)&u1)[k]), x2 = bf2f(((ushort*)&u2)[k]);
        ((ushort*)&o1)[k] = f2bf(x1 * c - x2 * s);
        ((ushort*)&o2)[k] = f2bf(x1 * s + x2 * c);
    }
    *(ushort4*)&Q[row * 768 + j4] = o1;
    *(ushort4*)&Q[row * 768 + 384 + j4] = o2;
}

// ---------------- RoPE(x) -> Kr bf16 (layout [b][t][768]) ----------------
__global__ void k_ropek(const float* __restrict__ x, ushort* __restrict__ Kr,
                        const int* __restrict__ pos, int nrows) {
    int i = blockIdx.x * blockDim.x + threadIdx.x;
    int row = i / 96, j4 = (i % 96) * 4;
    if (row >= nrows) return;
    float p = (float)pos[row & 2047];
    float4 x1 = *(const float4*)&x[row * 768 + j4];
    float4 x2 = *(const float4*)&x[row * 768 + 384 + j4];
    ushort4 o1, o2;
    float a1[4] = {x1.x, x1.y, x1.z, x1.w};
    float a2[4] = {x2.x, x2.y, x2.z, x2.w};
#pragma unroll
    for (int k = 0; k < 4; k++) {
        float inv = exp2f(-(float)(j4 + k) * (13.287712379549449f / 384.0f));
        float ang = p * inv;
        float s, c; sincosf(ang, &s, &c);
        ((ushort*)&o1)[k] = f2bf(a1[k] * c - a2[k] * s);
        ((ushort*)&o2)[k] = f2bf(a1[k] * s + a2[k] * c);
    }
    *(ushort4*)&Kr[row * 768 + j4] = o1;
    *(ushort4*)&Kr[row * 768 + 384 + j4] = o2;
}

// ---------------- Flash attention v2 ----------------
// QBLK=64, KBLK=64, 1024 threads (16 waves, 4x4 wave grid), 1 block/CU.
// Q staged once per tile (6 chunks of [64][128], swizzled). K/V streamed through
// a 2x16KB double buffer via async global_load_lds (pre-swizzled source).
// Block handles tile pair (p, 31-p): exactly 33 kv-iters -> perfect balance.
// Per-head output written over Qr rows (block owns them exclusively).
__global__ __launch_bounds__(1024, 4) void k_attn(const ushort* Qr, const ushort* __restrict__ Kr,
                                                  const ushort* __restrict__ valT, ushort* Oh) {
    __shared__ ushort Qs[6 * 8192];     // [chunk][64 rows][128 cols] bf16, swizzled
    __shared__ ushort Kc[2][8192];      // K: [64][128]; V: [128][64]; swizzled
    __shared__ float  S_lds[64][68];
    __shared__ ushort P_lds[64 * 72];
    __shared__ float  resc_s[64], l_s[64];

    const int p = blockIdx.x, hh = blockIdx.y, b = blockIdx.z;
    const int bh = b * 8 + hh;
    const int tid = threadIdx.x, lane = tid & 63, wid = tid >> 6;
    const int wr = wid >> 2, wc = wid & 3;          // 4x4 wave grid
    const int l15 = lane & 15, l4 = lane >> 4;
    const int srow = tid >> 4, slg = tid & 15;      // softmax role: 16 lanes per row

    // staging geometry (dest linear = tid*16 bytes within a 16KB chunk)
    const int krow = tid >> 4;                                   // K/Q: 64 rows x 256B
    const int koff = ((tid & 15) * 16) ^ ((krow & 7) << 4);      // pre-swizzled src offset
    const int vrow = tid >> 3;                                   // V: 128 rows x 128B
    const int voff = ((tid & 7) * 16) ^ ((vrow & 7) << 4);
    ushort* kdst0 = Kc[0] + wid * 512;   // wave-uniform dest base (shorts)
    ushort* kdst1 = Kc[1] + wid * 512;

    const int ra = wr * 16 + l15, rb_ = wc * 16 + l15;
    const int sa = (ra & 7) << 4, sb = (rb_ & 7) << 4;

    for (int ti = 0; ti < 2; ti++) {
        const int qt = ti ? (31 - p) : p;
        const int q0 = qt * 64;

        // issue Q staging (6 chunks) + K chunk0 of kb=0
        const char* qsrc = (const char*)Qr + ((size_t)(bh * 2048 + q0 + krow) * 768) * 2 + koff;
#pragma unroll
        for (int c = 0; c < 6; c++)
            gload16(qsrc + c * 256, Qs + c * 8192 + wid * 512);
        {
            const char* k0 = (const char*)Kr + ((size_t)(b * 2048 + krow) * 768) * 2 + koff;
            gload16(k0, kdst0);
        }

        float m_r = NEGINF, l_r = 0.f;
        f32x4 oacc[6][2] = {};

        for (int kb = 0; kb <= qt; kb++) {
            const char* kbase = (const char*)Kr + ((size_t)(b * 2048 + kb * 64 + krow) * 768) * 2 + koff;
            const char* vbase = (const char*)valT + ((size_t)(bh * 768 + vrow) * 2048 + kb * 64) * 2 + voff;

            // ---- QK^T: 6 d-chunks, double-buffered ----
            f32x4 s = {};
#pragma unroll
            for (int c = 0; c < 6; c++) {
                __syncthreads();                       // chunk c landed; buf[(c+1)&1] free
                if (c < 5)      gload16(kbase + (c + 1) * 256, (c & 1) ? kdst0 : kdst1);
                else            gload16(vbase, kdst0); // V chunk 0
                const char* qc = (const char*)Qs + c * 16384;
                const char* kcb = (const char*)Kc[c & 1];
#pragma unroll
                for (int ks = 0; ks < 4; ks++) {
                    int kbyte = ks * 64 + l4 * 16;
                    bf16x8 a  = *(const bf16x8*)(qc  + ra  * 256 + (kbyte ^ sa));
                    bf16x8 bb = *(const bf16x8*)(kcb + rb_ * 256 + (kbyte ^ sb));
                    s = __builtin_amdgcn_mfma_f32_16x16x32_bf16(a, bb, s, 0, 0, 0);
                }
            }

            // ---- S -> LDS, softmax (m,l in regs), P -> LDS ----
#pragma unroll
            for (int r = 0; r < 4; r++)
                S_lds[wr * 16 + l4 * 4 + r][wc * 16 + l15] = s[r];
            __syncthreads();                           // S visible; V0 drained
            gload16(vbase + 524288, kdst1);            // V chunk 1

            float4 sv = *(const float4*)&S_lds[srow][slg * 4];
            float vv[4];
            const bool diag = (kb == qt);
            const int grow = q0 + srow, cb = kb * 64 + slg * 4;
            {
                const float* svp = (const float*)&sv;
#pragma unroll
                for (int j = 0; j < 4; j++) {
                    float v = svp[j] * SCALE;
                    if (diag && cb + j > grow) v = NEGINF;
                    vv[j] = v;
                }
            }
            float pmax = fmaxf(fmaxf(vv[0], vv[1]), fmaxf(vv[2], vv[3]));
#pragma unroll
            for (int m2 = 1; m2 < 16; m2 <<= 1) pmax = fmaxf(pmax, __shfl_xor(pmax, m2));
            float m_new = fmaxf(m_r, pmax);
            float rv = __expf(m_r - m_new);
            float psum = 0.f; ushort pb[4];
#pragma unroll
            for (int j = 0; j < 4; j++) {
                float pp = __expf(vv[j] - m_new);
                psum += pp; pb[j] = f2bf(pp);
            }
#pragma unroll
            for (int m2 = 1; m2 < 16; m2 <<= 1) psum += __shfl_xor(psum, m2);
            l_r = l_r * rv + psum; m_r = m_new;
            uint2 pw; pw.x = pb[0] | ((uint)pb[1] << 16); pw.y = pb[2] | ((uint)pb[3] << 16);
            *(uint2*)((char*)P_lds + srow * 144 + slg * 8) = pw;
            if (slg == 0) resc_s[srow] = rv;
            __syncthreads();                           // P + resc visible; V1 drained

            // ---- rescale O ----
            float4 rf = *(const float4*)&resc_s[wr * 16 + l4 * 4];
            const float* rfp = (const float*)&rf;
#pragma unroll
            for (int c = 0; c < 6; c++)
#pragma unroll
                for (int n = 0; n < 2; n++)
#pragma unroll
                    for (int r = 0; r < 4; r++) oacc[c][n][r] *= rfp[r];

            // ---- PV: 6 dd-chunks, double-buffered ----
#pragma unroll
            for (int c = 0; c < 6; c++) {
                const char* vcb = (const char*)Kc[c & 1];
#pragma unroll
                for (int kc2 = 0; kc2 < 2; kc2++) {
                    bf16x8 a = *(const bf16x8*)((const char*)P_lds + (wr * 16 + l15) * 144 + kc2 * 64 + l4 * 16);
#pragma unroll
                    for (int n = 0; n < 2; n++) {
                        int rvr = wc * 32 + n * 16 + l15;
                        bf16x8 bb = *(const bf16x8*)(vcb + rvr * 128 + ((kc2 * 64 + l4 * 16) ^ ((rvr & 7) << 4)));
                        oacc[c][n] = __builtin_amdgcn_mfma_f32_16x16x32_bf16(a, bb, oacc[c][n], 0, 0, 0);
                    }
                }
                __syncthreads();                       // all reads of buf[c&1] done
                if (c <= 3)      gload16(vbase + (size_t)(c + 2) * 524288, (c & 1) ? kdst1 : kdst0);
                else if (c == 4 && kb < qt) {
                    const char* kn = (const char*)Kr + ((size_t)(b * 2048 + (kb + 1) * 64 + krow) * 768) * 2 + koff;
                    gload16(kn, kdst0);                // next-iter K chunk 0
                }
            }
        }

        // ---- epilogue: divide by l, write per-head output over Qr rows ----
        if (slg == 0) l_s[srow] = l_r;
        __syncthreads();
        float4 lf = *(const float4*)&l_s[wr * 16 + l4 * 4];
        const float* lfp = (const float*)&lf;
        float inv[4];
#pragma unroll
        for (int r = 0; r < 4; r++) inv[r] = 1.0f / lfp[r];
        ushort* orow = Oh + (size_t)(bh * 2048 + q0) * 768;
#pragma unroll
        for (int c = 0; c < 6; c++)
#pragma unroll
            for (int n = 0; n < 2; n++) {
                int dd = c * 128 + wc * 32 + n * 16 + l15;
#pragma unroll
                for (int r = 0; r < 4; r++)
                    orow[(size_t)(wr * 16 + l4 * 4 + r) * 768 + dd] = f2bf(oacc[c][n][r] * inv[r]);
            }
    }
}

// ---------------- head-sum reduce: out[b][t][d] = sum_h Oh[b][h][t][d] ----------------
__global__ void k_reduce(const ushort* __restrict__ Oh, float* __restrict__ out) {
    int i = blockIdx.x * blockDim.x + threadIdx.x;
    if (i >= 786432) return;                 // 2*2048*768/4
    size_t base = (size_t)i * 4;
    int b = (base >= 1572864) ? 1 : 0;       // 2048*768 = 1572864
    size_t rem = base - (size_t)b * 1572864;
    const ushort* src = Oh + (size_t)b * 8 * 1572864 + rem;
    float4 acc = {0.f, 0.f, 0.f, 0.f};
#pragma unroll
    for (int h = 0; h < 8; h++) {
        ushort4 v = *(const ushort4*)(src + (size_t)h * 1572864);
        acc.x += bf2f(v.x); acc.y += bf2f(v.y); acc.z += bf2f(v.z); acc.w += bf2f(v.w);
    }
    *(float4*)&out[base] = acc;
}

extern "C" void kernel_launch(void* const* d_in, const int* in_sizes, int n_in,
                              void* d_out, int out_size, void* d_ws, size_t ws_size,
                              hipStream_t stream) {
    const float* x = (const float*)d_in[0];
    const float* M = (const float*)d_in[1];
    const float* V = (const float*)d_in[2];
    const int* pos = (const int*)d_in[3];
    float* out = (float*)d_out;
    char* ws = (char*)d_ws;

    // workspace layout (bytes)
    ushort* xb   = (ushort*)(ws);                 //  6,291,456  x bf16 [4096][768]
    ushort* Mt   = (ushort*)(ws + 6291456);       //  9,437,184  M^T bf16 [6144][768]
    ushort* Vt   = (ushort*)(ws + 15728640);      //  9,437,184  V^T bf16 [6144][768]
    ushort* Qr   = (ushort*)(ws + 25165824);      // 50,331,648  Q bf16 [b][h][t][768] (later Oh)
    ushort* valT = (ushort*)(ws + 75497472);      // 50,331,648  val^T bf16 [b][h][dd][t]
    ushort* Kr   = (ushort*)(ws + 125829120);     //  6,291,456  K bf16 [b][t][768]

    k_convx<<<3072, 256, 0, stream>>>(x, xb, 786432);
    k_tconv<<<dim3(24, 192), 256, 0, stream>>>(M, Mt, 768, 6144);
    k_tconv<<<dim3(24, 192), 256, 0, stream>>>(V, Vt, 768, 6144);
    k_gemm<0><<<dim3(32, 48), 256, 0, stream>>>(xb, Mt, Qr);
    k_gemm<1><<<dim3(48, 32), 256, 0, stream>>>(Vt, xb, valT);
    k_ropeq<<<12288, 256, 0, stream>>>(Qr, pos, 32768);
    k_ropek<<<1536, 256, 0, stream>>>(x, Kr, pos, 4096);
    k_attn<<<dim3(16, 8, 2), 1024, 0, stream>>>(Qr, Kr, valT, Qr /*Oh overwrites Qr*/);
    k_reduce<<<3072, 256, 0, stream>>>(Qr, out);
}

// Round 3
// 404.745 us; speedup vs baseline: 3.0270x; 1.1086x over previous
//
#include <hip/hip_runtime.h>
#include <hip/hip_bf16.h>

typedef __bf16 bf16x8 __attribute__((ext_vector_type(8)));
typedef float f32x4 __attribute__((ext_vector_type(4)));

// B=2, T=2048, d=768, h=8
#define SCALE 0.03608439182435161f   // 1/sqrt(768)
#define NEGINF (-1e30f)

static __device__ __forceinline__ ushort f2bf(float f) {
    union { float f; unsigned u; } v; v.f = f;
    unsigned r = (v.u + 0x7fff + ((v.u >> 16) & 1)) >> 16;  // RTE
    return (ushort)r;
}
static __device__ __forceinline__ float bf2f(ushort u) {
    union { unsigned u; float f; } v; v.u = ((unsigned)u) << 16;
    return v.f;
}

// async 16B global -> LDS (dest: wave-uniform base + lane*16)
static __device__ __forceinline__ void gload16(const void* g, void* lds) {
    __builtin_amdgcn_global_load_lds((const __attribute__((address_space(1))) void*)g,
                                     (__attribute__((address_space(3))) void*)lds, 16, 0, 0);
}

// counted-vmcnt barriers (T4): loads stay in flight across the barrier
#define BARV1 do { asm volatile("s_waitcnt vmcnt(1)" ::: "memory"); \
                   __builtin_amdgcn_s_barrier(); \
                   asm volatile("" ::: "memory"); } while (0)
#define BARV0 do { asm volatile("s_waitcnt vmcnt(0)" ::: "memory"); \
                   __builtin_amdgcn_s_barrier(); \
                   asm volatile("" ::: "memory"); } while (0)
#define BARL  do { asm volatile("s_waitcnt lgkmcnt(0)" ::: "memory"); \
                   __builtin_amdgcn_s_barrier(); \
                   asm volatile("" ::: "memory"); } while (0)

// ---------------- f32 -> bf16 convert (x) ----------------
__global__ void k_convx(const float* __restrict__ x, ushort* __restrict__ xb, int n4) {
    int i = blockIdx.x * blockDim.x + threadIdx.x;
    if (i >= n4) return;
    float4 v = ((const float4*)x)[i];
    ushort4 o; o.x = f2bf(v.x); o.y = f2bf(v.y); o.z = f2bf(v.z); o.w = f2bf(v.w);
    ((ushort4*)xb)[i] = o;
}

// ---------------- f32 [R][C] -> bf16 [C][R] transpose-convert ----------------
__global__ void k_tconv(const float* __restrict__ in, ushort* __restrict__ out, int R, int C) {
    __shared__ float ts[32][33];
    int r0 = blockIdx.x * 32, c0 = blockIdx.y * 32;
    int lr = threadIdx.x >> 5, lc = threadIdx.x & 31;
#pragma unroll
    for (int i = 0; i < 4; i++) ts[lr + i * 8][lc] = in[(r0 + lr + i * 8) * C + c0 + lc];
    __syncthreads();
#pragma unroll
    for (int i = 0; i < 4; i++) out[(c0 + lr + i * 8) * R + r0 + lc] = f2bf(ts[lc][lr + i * 8]);
}

// ---------------- bf16 GEMM: C[M][N] = A[M][768] * Bt[N][768]^T ----------------
template <int EPI>
__global__ __launch_bounds__(256) void k_gemm(const ushort* __restrict__ A,
                                              const ushort* __restrict__ Bt,
                                              ushort* __restrict__ out) {
    __shared__ ushort As[128 * 40];
    __shared__ ushort Bs[128 * 40];
    const int m0 = blockIdx.x * 128, n0 = blockIdx.y * 128;
    const int tid = threadIdx.x, lane = tid & 63, wid = tid >> 6;
    const int wm = (wid >> 1) * 64, wn = (wid & 1) * 64;
    f32x4 acc[4][4] = {};

    for (int kt = 0; kt < 768; kt += 32) {
#pragma unroll
        for (int i = 0; i < 2; i++) {
            int c = tid + i * 256;
            int row = c >> 2, kc = (c & 3) * 8;
            uint4 va = *(const uint4*)&A[(m0 + row) * 768 + kt + kc];
            *(uint4*)&As[row * 40 + kc] = va;
            uint4 vb = *(const uint4*)&Bt[(n0 + row) * 768 + kt + kc];
            *(uint4*)&Bs[row * 40 + kc] = vb;
        }
        __syncthreads();
        bf16x8 af[4], bfr[4];
#pragma unroll
        for (int m = 0; m < 4; m++)
            af[m] = *(const bf16x8*)&As[(wm + m * 16 + (lane & 15)) * 40 + (lane >> 4) * 8];
#pragma unroll
        for (int n = 0; n < 4; n++)
            bfr[n] = *(const bf16x8*)&Bs[(wn + n * 16 + (lane & 15)) * 40 + (lane >> 4) * 8];
#pragma unroll
        for (int m = 0; m < 4; m++)
#pragma unroll
            for (int n = 0; n < 4; n++)
                acc[m][n] = __builtin_amdgcn_mfma_f32_16x16x32_bf16(af[m], bfr[n], acc[m][n], 0, 0, 0);
        __syncthreads();
    }

#pragma unroll
    for (int m = 0; m < 4; m++) {
#pragma unroll
        for (int n = 0; n < 4; n++) {
#pragma unroll
            for (int r = 0; r < 4; r++) {
                int row = m0 + wm + m * 16 + (lane >> 4) * 4 + r;
                int col = n0 + wn + n * 16 + (lane & 15);
                float v = acc[m][n][r];
                int idx;
                if (EPI == 0) {
                    int b = row >> 11, t = row & 2047;
                    int hh = col / 768, dd = col - hh * 768;
                    idx = ((b * 8 + hh) * 2048 + t) * 768 + dd;
                } else {
                    int hh = row / 768, dd = row - hh * 768;
                    int b = col >> 11, t = col & 2047;
                    idx = ((b * 8 + hh) * 768 + dd) * 2048 + t;
                }
                out[idx] = f2bf(v);
            }
        }
    }
}

// ---------------- RoPE on Q in-place (bf16, layout [b][h][t][768]); folds SCALE ----------------
__global__ void k_ropeq(ushort* __restrict__ Q, const int* __restrict__ pos, int nrows) {
    int i = blockIdx.x * blockDim.x + threadIdx.x;
    int row = i / 96, j4 = (i % 96) * 4;
    if (row >= nrows) return;
    float p = (float)pos[row & 2047];
    ushort4 u1 = *(ushort4*)&Q[row * 768 + j4];
    ushort4 u2 = *(ushort4*)&Q[row * 768 + 384 + j4];
    ushort4 o1, o2;
#pragma unroll
    for (int k = 0; k < 4; k++) {
        float inv = exp2f(-(float)(j4 + k) * (13.287712379549449f / 384.0f));
        float ang = p * inv;
        float s, c; sincosf(ang, &s, &c);
        float x1 = bf2f(((ushort*)&u1)[k]), x2 = bf2f(((ushort*)&u2)[k]);
        ((ushort*)&o1)[k] = f2bf((x1 * c - x2 * s) * SCALE);
        ((ushort*)&o2)[k] = f2bf((x1 * s + x2 * c) * SCALE);
    }
    *(ushort4*)&Q[row * 768 + j4] = o1;
    *(ushort4*)&Q[row * 768 + 384 + j4] = o2;
}

// ---------------- RoPE(x) -> Kr bf16 (layout [b][t][768]) ----------------
__global__ void k_ropek(const float* __restrict__ x, ushort* __restrict__ Kr,
                        const int* __restrict__ pos, int nrows) {
    int i = blockIdx.x * blockDim.x + threadIdx.x;
    int row = i / 96, j4 = (i % 96) * 4;
    if (row >= nrows) return;
    float p = (float)pos[row & 2047];
    float4 x1 = *(const float4*)&x[row * 768 + j4];
    float4 x2 = *(const float4*)&x[row * 768 + 384 + j4];
    ushort4 o1, o2;
    float a1[4] = {x1.x, x1.y, x1.z, x1.w};
    float a2[4] = {x2.x, x2.y, x2.z, x2.w};
#pragma unroll
    for (int k = 0; k < 4; k++) {
        float inv = exp2f(-(float)(j4 + k) * (13.287712379549449f / 384.0f));
        float ang = p * inv;
        float s, c; sincosf(ang, &s, &c);
        ((ushort*)&o1)[k] = f2bf(a1[k] * c - a2[k] * s);
        ((ushort*)&o2)[k] = f2bf(a1[k] * s + a2[k] * c);
    }
    *(ushort4*)&Kr[row * 768 + j4] = o1;
    *(ushort4*)&Kr[row * 768 + 384 + j4] = o2;
}

// ---------------- Flash attention v3: counted-vmcnt 3-buffer pipeline ----------------
// QBLK=64, KBLK=64, 1024 threads (16 waves, 4x4 grid), 1 block/CU.
// Chunks stream K0..K5 (QK^T) then V0..V5 (PV), buffer = chunk%3, issued 2 phases
// ahead; per-phase wait is s_waitcnt vmcnt(1) + s_barrier (loads never drained to 0
// in the main loop). S and P share one bf16 LDS buffer (P overwrites S in place).
__global__ __launch_bounds__(1024, 4) void k_attn(const ushort* Qr, const ushort* __restrict__ Kr,
                                                  const ushort* __restrict__ valT, ushort* Oh) {
    __shared__ ushort Qs[6 * 8192];     // [chunk][64 rows][128 cols] bf16, swizzled
    __shared__ ushort Buf[3][8192];     // K: [64][128]; V: [128][64]; swizzled
    __shared__ ushort SP[64 * 72];      // S then P, bf16, row stride 144B
    __shared__ float  resc_s[64], l_s[64];

    const int p = blockIdx.x, hh = blockIdx.y, b = blockIdx.z;
    const int bh = b * 8 + hh;
    const int tid = threadIdx.x, lane = tid & 63, wid = tid >> 6;
    const int wr = wid >> 2, wc = wid & 3;          // 4x4 wave grid
    const int l15 = lane & 15, l4 = lane >> 4;
    const int srow = tid >> 4, slg = tid & 15;      // softmax role: 16 lanes per row

    // staging geometry (dest linear = tid*16 bytes within a 16KB chunk)
    const int krow = tid >> 4;                                   // K/Q: 64 rows x 256B
    const int koff = ((tid & 15) * 16) ^ ((krow & 7) << 4);      // pre-swizzled src offset
    const int vrow = tid >> 3;                                   // V: 128 rows x 128B
    const int voff = ((tid & 7) * 16) ^ ((vrow & 7) << 4);

    const char* Kptr = (const char*)Kr + (size_t)b * 2048 * 1536 + (size_t)krow * 1536 + koff;
    const char* Vptr = (const char*)valT + ((size_t)bh * 768 + vrow) * 4096 + voff;

    const int ra = wr * 16 + l15, rb_ = wc * 16 + l15;
    const int sa = (ra & 7) << 4, sb = (rb_ & 7) << 4;

    for (int ti = 0; ti < 2; ti++) {
        const int qt = ti ? (31 - p) : p;
        const int q0 = qt * 64;

        // prologue: issue Q (6 chunks) + K0 + K1
        const char* qp = (const char*)Qr + ((size_t)(bh * 2048 + q0 + krow)) * 1536 + koff;
#pragma unroll
        for (int c = 0; c < 6; c++)
            gload16(qp + c * 256, Qs + c * 8192 + wid * 512);
        gload16(Kptr, Buf[0] + wid * 512);
        gload16(Kptr + 256, Buf[1] + wid * 512);

        float m_r = NEGINF, l_r = 0.f;
        f32x4 oacc[6][2] = {};

        for (int kb = 0; kb <= qt; kb++) {
            const char* kpc = Kptr + (size_t)kb * 98304;
            const char* vpc = Vptr + (size_t)kb * 128;
            const char* kpn = kpc + 98304;

            // ---- QK^T: 6 d-chunk phases ----
            f32x4 s = {};
#pragma unroll
            for (int c = 0; c < 6; c++) {
                BARV1;                                   // chunk c landed (1 stays in flight)
                if (c < 4)       gload16(kpc + (c + 2) * 256, Buf[(c + 2) % 3] + wid * 512);
                else if (c == 4) gload16(vpc,                 Buf[0] + wid * 512);
                else             gload16(vpc + 524288,        Buf[1] + wid * 512);
                const char* qc  = (const char*)Qs + c * 16384;
                const char* kcb = (const char*)Buf[c % 3];
                __builtin_amdgcn_s_setprio(1);
#pragma unroll
                for (int ks = 0; ks < 4; ks++) {
                    int kbyte = ks * 64 + l4 * 16;
                    bf16x8 a  = *(const bf16x8*)(qc  + ra  * 256 + (kbyte ^ sa));
                    bf16x8 bb = *(const bf16x8*)(kcb + rb_ * 256 + (kbyte ^ sb));
                    s = __builtin_amdgcn_mfma_f32_16x16x32_bf16(a, bb, s, 0, 0, 0);
                }
                __builtin_amdgcn_s_setprio(0);
            }

            // ---- S -> LDS (bf16) ----
#pragma unroll
            for (int r = 0; r < 4; r++)
                *(ushort*)((char*)SP + (wr * 16 + l4 * 4 + r) * 144 + (wc * 16 + l15) * 2) = f2bf(s[r]);
            BARL;

            // ---- softmax (m,l in regs); P overwrites S in place ----
            {
                uint2 sw = *(const uint2*)((const char*)SP + srow * 144 + slg * 8);
                float vv[4];
                vv[0] = bf2f((ushort)(sw.x & 0xffffu));
                vv[1] = bf2f((ushort)(sw.x >> 16));
                vv[2] = bf2f((ushort)(sw.y & 0xffffu));
                vv[3] = bf2f((ushort)(sw.y >> 16));
                if (kb == qt) {
                    const int grow = q0 + srow, cb = kb * 64 + slg * 4;
#pragma unroll
                    for (int j = 0; j < 4; j++) if (cb + j > grow) vv[j] = NEGINF;
                }
                float pmax = fmaxf(fmaxf(vv[0], vv[1]), fmaxf(vv[2], vv[3]));
#pragma unroll
                for (int m2 = 1; m2 < 16; m2 <<= 1) pmax = fmaxf(pmax, __shfl_xor(pmax, m2));
                float m_new = fmaxf(m_r, pmax);
                float rv = __expf(m_r - m_new);
                float psum = 0.f; ushort pb[4];
#pragma unroll
                for (int j = 0; j < 4; j++) {
                    float pp = __expf(vv[j] - m_new);
                    psum += pp; pb[j] = f2bf(pp);
                }
#pragma unroll
                for (int m2 = 1; m2 < 16; m2 <<= 1) psum += __shfl_xor(psum, m2);
                l_r = l_r * rv + psum; m_r = m_new;
                uint2 pw; pw.x = pb[0] | ((uint)pb[1] << 16); pw.y = pb[2] | ((uint)pb[3] << 16);
                *(uint2*)((char*)SP + srow * 144 + slg * 8) = pw;
                if (slg == 0) resc_s[srow] = rv;
            }
            BARL;

            // ---- rescale O; hoist P fragments (once per iter) ----
            float4 rf = *(const float4*)&resc_s[wr * 16 + l4 * 4];
            const float* rfp = (const float*)&rf;
#pragma unroll
            for (int c = 0; c < 6; c++)
#pragma unroll
                for (int n = 0; n < 2; n++)
#pragma unroll
                    for (int r = 0; r < 4; r++) oacc[c][n][r] *= rfp[r];
            bf16x8 pa0 = *(const bf16x8*)((const char*)SP + (wr * 16 + l15) * 144 + l4 * 16);
            bf16x8 pa1 = *(const bf16x8*)((const char*)SP + (wr * 16 + l15) * 144 + 64 + l4 * 16);

            // ---- PV: 6 dd-chunk phases ----
#pragma unroll
            for (int c = 0; c < 6; c++) {
                if (c < 5) { BARV1; }
                else if (kb < qt) { BARV1; }
                else { BARV0; }
                if (c < 4) gload16(vpc + (size_t)(c + 2) * 524288, Buf[(c + 2) % 3] + wid * 512);
                else if (kb < qt) {
                    if (c == 4) gload16(kpn,       Buf[0] + wid * 512);
                    else        gload16(kpn + 256, Buf[1] + wid * 512);
                }
                const char* vcb = (const char*)Buf[c % 3];
                __builtin_amdgcn_s_setprio(1);
#pragma unroll
                for (int kc2 = 0; kc2 < 2; kc2++) {
                    bf16x8 a = kc2 ? pa1 : pa0;
#pragma unroll
                    for (int n = 0; n < 2; n++) {
                        int rvr = wc * 32 + n * 16 + l15;
                        bf16x8 bb = *(const bf16x8*)(vcb + rvr * 128 + ((kc2 * 64 + l4 * 16) ^ ((rvr & 7) << 4)));
                        oacc[c][n] = __builtin_amdgcn_mfma_f32_16x16x32_bf16(a, bb, oacc[c][n], 0, 0, 0);
                    }
                }
                __builtin_amdgcn_s_setprio(0);
            }
        }

        // ---- epilogue: divide by l, write per-head output over Qr rows ----
        if (slg == 0) l_s[srow] = l_r;
        BARL;
        float4 lf = *(const float4*)&l_s[wr * 16 + l4 * 4];
        const float* lfp = (const float*)&lf;
        float inv_[4];
#pragma unroll
        for (int r = 0; r < 4; r++) inv_[r] = 1.0f / lfp[r];
        ushort* orow = Oh + (size_t)(bh * 2048 + q0) * 768;
#pragma unroll
        for (int c = 0; c < 6; c++)
#pragma unroll
            for (int n = 0; n < 2; n++) {
                int dd = c * 128 + wc * 32 + n * 16 + l15;
#pragma unroll
                for (int r = 0; r < 4; r++)
                    orow[(size_t)(wr * 16 + l4 * 4 + r) * 768 + dd] = f2bf(oacc[c][n][r] * inv_[r]);
            }
    }
}

// ---------------- head-sum reduce: out[b][t][d] = sum_h Oh[b][h][t][d] ----------------
__global__ void k_reduce(const ushort* __restrict__ Oh, float* __restrict__ out) {
    int i = blockIdx.x * blockDim.x + threadIdx.x;
    if (i >= 786432) return;                 // 2*2048*768/4
    size_t base = (size_t)i * 4;
    int b = (base >= 1572864) ? 1 : 0;       // 2048*768 = 1572864
    size_t rem = base - (size_t)b * 1572864;
    const ushort* src = Oh + (size_t)b * 8 * 1572864 + rem;
    float4 acc = {0.f, 0.f, 0.f, 0.f};
#pragma unroll
    for (int h = 0; h < 8; h++) {
        ushort4 v = *(const ushort4*)(src + (size_t)h * 1572864);
        acc.x += bf2f(v.x); acc.y += bf2f(v.y); acc.z += bf2f(v.z); acc.w += bf2f(v.w);
    }
    *(float4*)&out[base] = acc;
}

extern "C" void kernel_launch(void* const* d_in, const int* in_sizes, int n_in,
                              void* d_out, int out_size, void* d_ws, size_t ws_size,
                              hipStream_t stream) {
    const float* x = (const float*)d_in[0];
    const float* M = (const float*)d_in[1];
    const float* V = (const float*)d_in[2];
    const int* pos = (const int*)d_in[3];
    float* out = (float*)d_out;
    char* ws = (char*)d_ws;

    // workspace layout (bytes)
    ushort* xb   = (ushort*)(ws);                 //  6,291,456  x bf16 [4096][768]
    ushort* Mt   = (ushort*)(ws + 6291456);       //  9,437,184  M^T bf16 [6144][768]
    ushort* Vt   = (ushort*)(ws + 15728640);      //  9,437,184  V^T bf16 [6144][768]
    ushort* Qr   = (ushort*)(ws + 25165824);      // 50,331,648  Q bf16 [b][h][t][768] (later Oh)
    ushort* valT = (ushort*)(ws + 75497472);      // 50,331,648  val^T bf16 [b][h][dd][t]
    ushort* Kr   = (ushort*)(ws + 125829120);     //  6,291,456  K bf16 [b][t][768]

    k_convx<<<3072, 256, 0, stream>>>(x, xb, 786432);
    k_tconv<<<dim3(24, 192), 256, 0, stream>>>(M, Mt, 768, 6144);
    k_tconv<<<dim3(24, 192), 256, 0, stream>>>(V, Vt, 768, 6144);
    k_gemm<0><<<dim3(32, 48), 256, 0, stream>>>(xb, Mt, Qr);
    k_gemm<1><<<dim3(48, 32), 256, 0, stream>>>(Vt, xb, valT);
    k_ropeq<<<12288, 256, 0, stream>>>(Qr, pos, 32768);
    k_ropek<<<1536, 256, 0, stream>>>(x, Kr, pos, 4096);
    k_attn<<<dim3(16, 8, 2), 1024, 0, stream>>>(Qr, Kr, valT, Qr /*Oh overwrites Qr*/);
    k_reduce<<<3072, 256, 0, stream>>>(Qr, out);
}

// Round 4
// 371.586 us; speedup vs baseline: 3.2972x; 1.0892x over previous
//
#include <hip/hip_runtime.h>
#include <hip/hip_bf16.h>

typedef __bf16 bf16x8 __attribute__((ext_vector_type(8)));
typedef float f32x4 __attribute__((ext_vector_type(4)));
typedef float f32x16 __attribute__((ext_vector_type(16)));

// B=2, T=2048, d=768, h=8
#define SCALE 0.03608439182435161f   // 1/sqrt(768)
#define NEGINF (-1e30f)

static __device__ __forceinline__ ushort f2bf(float f) {
    union { float f; unsigned u; } v; v.f = f;
    unsigned r = (v.u + 0x7fff + ((v.u >> 16) & 1)) >> 16;  // RTE
    return (ushort)r;
}
static __device__ __forceinline__ float bf2f(ushort u) {
    union { unsigned u; float f; } v; v.u = ((unsigned)u) << 16;
    return v.f;
}

// async 16B global -> LDS (dest: wave-uniform base + lane*16)
static __device__ __forceinline__ void gload16(const void* g, void* lds) {
    __builtin_amdgcn_global_load_lds((const __attribute__((address_space(1))) void*)g,
                                     (__attribute__((address_space(3))) void*)lds, 16, 0, 0);
}

#define PHASE_SYNC do { asm volatile("s_waitcnt vmcnt(0) lgkmcnt(0)" ::: "memory"); \
                        __builtin_amdgcn_s_barrier(); \
                        asm volatile("" ::: "memory"); } while (0)
#define BARL do { asm volatile("s_waitcnt lgkmcnt(0)" ::: "memory"); \
                  __builtin_amdgcn_s_barrier(); \
                  asm volatile("" ::: "memory"); } while (0)

// ---------------- f32 -> bf16 convert (x) ----------------
__global__ void k_convx(const float* __restrict__ x, ushort* __restrict__ xb, int n4) {
    int i = blockIdx.x * blockDim.x + threadIdx.x;
    if (i >= n4) return;
    float4 v = ((const float4*)x)[i];
    ushort4 o; o.x = f2bf(v.x); o.y = f2bf(v.y); o.z = f2bf(v.z); o.w = f2bf(v.w);
    ((ushort4*)xb)[i] = o;
}

// ---------------- f32 [R][C] -> bf16 [C][R] transpose-convert ----------------
__global__ void k_tconv(const float* __restrict__ in, ushort* __restrict__ out, int R, int C) {
    __shared__ float ts[32][33];
    int r0 = blockIdx.x * 32, c0 = blockIdx.y * 32;
    int lr = threadIdx.x >> 5, lc = threadIdx.x & 31;
#pragma unroll
    for (int i = 0; i < 4; i++) ts[lr + i * 8][lc] = in[(r0 + lr + i * 8) * C + c0 + lc];
    __syncthreads();
#pragma unroll
    for (int i = 0; i < 4; i++) out[(c0 + lr + i * 8) * R + r0 + lc] = f2bf(ts[lc][lr + i * 8]);
}

// ---------------- bf16 GEMM: C[M][N] = A[M][768] * Bt[N][768]^T ----------------
template <int EPI>
__global__ __launch_bounds__(256) void k_gemm(const ushort* __restrict__ A,
                                              const ushort* __restrict__ Bt,
                                              ushort* __restrict__ out) {
    __shared__ ushort As[128 * 40];
    __shared__ ushort Bs[128 * 40];
    const int m0 = blockIdx.x * 128, n0 = blockIdx.y * 128;
    const int tid = threadIdx.x, lane = tid & 63, wid = tid >> 6;
    const int wm = (wid >> 1) * 64, wn = (wid & 1) * 64;
    f32x4 acc[4][4] = {};

    for (int kt = 0; kt < 768; kt += 32) {
#pragma unroll
        for (int i = 0; i < 2; i++) {
            int c = tid + i * 256;
            int row = c >> 2, kc = (c & 3) * 8;
            uint4 va = *(const uint4*)&A[(m0 + row) * 768 + kt + kc];
            *(uint4*)&As[row * 40 + kc] = va;
            uint4 vb = *(const uint4*)&Bt[(n0 + row) * 768 + kt + kc];
            *(uint4*)&Bs[row * 40 + kc] = vb;
        }
        __syncthreads();
        bf16x8 af[4], bfr[4];
#pragma unroll
        for (int m = 0; m < 4; m++)
            af[m] = *(const bf16x8*)&As[(wm + m * 16 + (lane & 15)) * 40 + (lane >> 4) * 8];
#pragma unroll
        for (int n = 0; n < 4; n++)
            bfr[n] = *(const bf16x8*)&Bs[(wn + n * 16 + (lane & 15)) * 40 + (lane >> 4) * 8];
#pragma unroll
        for (int m = 0; m < 4; m++)
#pragma unroll
            for (int n = 0; n < 4; n++)
                acc[m][n] = __builtin_amdgcn_mfma_f32_16x16x32_bf16(af[m], bfr[n], acc[m][n], 0, 0, 0);
        __syncthreads();
    }

#pragma unroll
    for (int m = 0; m < 4; m++) {
#pragma unroll
        for (int n = 0; n < 4; n++) {
#pragma unroll
            for (int r = 0; r < 4; r++) {
                int row = m0 + wm + m * 16 + (lane >> 4) * 4 + r;
                int col = n0 + wn + n * 16 + (lane & 15);
                float v = acc[m][n][r];
                int idx;
                if (EPI == 0) {
                    int b = row >> 11, t = row & 2047;
                    int hh = col / 768, dd = col - hh * 768;
                    idx = ((b * 8 + hh) * 2048 + t) * 768 + dd;
                } else {
                    int hh = row / 768, dd = row - hh * 768;
                    int b = col >> 11, t = col & 2047;
                    idx = ((b * 8 + hh) * 768 + dd) * 2048 + t;
                }
                out[idx] = f2bf(v);
            }
        }
    }
}

// ---------------- RoPE on Q in-place (bf16, layout [b][h][t][768]); folds SCALE ----------------
__global__ void k_ropeq(ushort* __restrict__ Q, const int* __restrict__ pos, int nrows) {
    int i = blockIdx.x * blockDim.x + threadIdx.x;
    int row = i / 96, j4 = (i % 96) * 4;
    if (row >= nrows) return;
    float p = (float)pos[row & 2047];
    ushort4 u1 = *(ushort4*)&Q[row * 768 + j4];
    ushort4 u2 = *(ushort4*)&Q[row * 768 + 384 + j4];
    ushort4 o1, o2;
#pragma unroll
    for (int k = 0; k < 4; k++) {
        float inv = exp2f(-(float)(j4 + k) * (13.287712379549449f / 384.0f));
        float ang = p * inv;
        float s, c; sincosf(ang, &s, &c);
        float x1 = bf2f(((ushort*)&u1)[k]), x2 = bf2f(((ushort*)&u2)[k]);
        ((ushort*)&o1)[k] = f2bf((x1 * c - x2 * s) * SCALE);
        ((ushort*)&o2)[k] = f2bf((x1 * s + x2 * c) * SCALE);
    }
    *(ushort4*)&Q[row * 768 + j4] = o1;
    *(ushort4*)&Q[row * 768 + 384 + j4] = o2;
}

// ---------------- RoPE(x) -> Kr bf16 (layout [b][t][768]) ----------------
__global__ void k_ropek(const float* __restrict__ x, ushort* __restrict__ Kr,
                        const int* __restrict__ pos, int nrows) {
    int i = blockIdx.x * blockDim.x + threadIdx.x;
    int row = i / 96, j4 = (i % 96) * 4;
    if (row >= nrows) return;
    float p = (float)pos[row & 2047];
    float4 x1 = *(const float4*)&x[row * 768 + j4];
    float4 x2 = *(const float4*)&x[row * 768 + 384 + j4];
    ushort4 o1, o2;
    float a1[4] = {x1.x, x1.y, x1.z, x1.w};
    float a2[4] = {x2.x, x2.y, x2.z, x2.w};
#pragma unroll
    for (int k = 0; k < 4; k++) {
        float inv = exp2f(-(float)(j4 + k) * (13.287712379549449f / 384.0f));
        float ang = p * inv;
        float s, c; sincosf(ang, &s, &c);
        ((ushort*)&o1)[k] = f2bf(a1[k] * c - a2[k] * s);
        ((ushort*)&o2)[k] = f2bf(a1[k] * s + a2[k] * c);
    }
    *(ushort4*)&Kr[row * 768 + j4] = o1;
    *(ushort4*)&Kr[row * 768 + 384 + j4] = o2;
}

// ---------------- Flash attention v4: 32x32x16 MFMA, swapped-operand softmax ----------------
// QBLK=64, KBLK=128, 512 threads (8 waves), 1 block/CU.
// S^T = K*Q^T: 8 tiles of 32x32, one per wave (g=k-tile, qh=q-half). Softmax is
// lane-local (16 k-rows per lane, one q-col) + shfl_xor(32) + 4-entry LDS exchange.
// Q resident (96KB, 6 swizzled chunks). K/V stream through 2x32KB buffers; P(16KB)
// +stats(2.5KB) overlay the dead K5 buffer during the softmax window.
__global__ __launch_bounds__(512, 2) void k_attn(const ushort* Qr, const ushort* __restrict__ Kr,
                                                 const ushort* __restrict__ valT, ushort* Oh) {
    __shared__ alignas(128) char Qs[98304];     // [6][64 q][128 d] bf16, 16-deep XOR swizzle
    __shared__ alignas(128) char pool[65536];   // 2 x 32KB stream buffers

    const int p = blockIdx.x, hh = blockIdx.y, b = blockIdx.z;
    const int bh = b * 8 + hh;
    const int tid = threadIdx.x, lane = tid & 63, wid = tid >> 6;
    const int g = wid & 3, qh = wid >> 2;       // k-tile / q-half roles
    const int l31 = lane & 31, hi = lane >> 5;
    const int hi16 = hi << 4;

    // staging geometry: chunk = [128 rows][256B], dest linear = tid*16 per 8KB round
    const int row0 = tid >> 4, col16 = tid & 15;
    const int swz = (col16 << 4) ^ ((row0 & 15) << 4);   // pre-swizzled source column

    const int arow = g * 32 + l31;              // K row (QK A) / V dd-row (PV B)
    const int qrow = qh * 32 + l31;             // Q row (QK B) / P row (PV A) / lane's q
    const int asw = (arow & 15) << 4;
    const int qsw = (qrow & 15) << 4;

    char* Pb = pool + 32768;                    // P [64 q][128 k] bf16 (inside buf1)
    float* pmax_s = (float*)(pool + 49152);     // [64][4]
    float* psum_s = (float*)(pool + 50176);     // [64][4]
    float* stat_s = (float*)(pool + 51200);     // [64] resc / l

    const char* Kb0 = (const char*)Kr + ((size_t)(b * 2048 + row0)) * 1536 + swz;
    const char* Vb0 = (const char*)valT + ((size_t)(bh * 768 + row0)) * 4096 + swz;

    for (int ti = 0; ti < 2; ti++) {
        const int qt = ti ? (31 - p) : p;
        const int q0 = qt * 64;
        const int nkb = (qt + 2) >> 1;
        const int qg = q0 + qrow;

        // prologue: stage Q (6 chunks, 12 rounds) + K0 (4 rounds)
        const char* qsrc = (const char*)Qr + ((size_t)(bh * 2048 + q0 + row0)) * 1536 + swz;
#pragma unroll
        for (int r = 0; r < 12; r++)
            gload16(qsrc + (r >> 1) * 256 + (size_t)(r & 1) * 49152,
                    Qs + (r >> 1) * 16384 + (r & 1) * 8192 + wid * 1024);
#pragma unroll
        for (int r = 0; r < 4; r++)
            gload16(Kb0 + (size_t)r * 49152, pool + r * 8192 + wid * 1024);

        float m_r = NEGINF, l_r = 0.f;
        f32x16 oacc[6] = {};

        for (int kb = 0; kb < nkb; kb++) {
            const char* kc = Kb0 + (size_t)kb * 196608;   // +kb*128 rows
            const char* vc = Vb0 + (size_t)kb * 256;      // +kb*128 k-cols (bytes)

            // ---- QK^T: 6 d-chunk phases, S^T accumulated per wave ----
            f32x16 sacc = {};
#pragma unroll
            for (int c = 0; c < 6; c++) {
                PHASE_SYNC;                                // chunk c landed; other buf free
                if (c < 5) {
#pragma unroll
                    for (int r = 0; r < 4; r++)
                        gload16(kc + (c + 1) * 256 + (size_t)r * 49152,
                                pool + ((c + 1) & 1) * 32768 + r * 8192 + wid * 1024);
                } else {
#pragma unroll
                    for (int r = 0; r < 4; r++)            // V chunk 0 -> buf0
                        gload16(vc + (size_t)r * 131072, pool + r * 8192 + wid * 1024);
                }
                const char* kbuf = pool + (c & 1) * 32768;
                const char* qcb = Qs + c * 16384;
                __builtin_amdgcn_s_setprio(1);
#pragma unroll
                for (int s = 0; s < 8; s++) {
                    bf16x8 a = *(const bf16x8*)(kbuf + arow * 256 + ((s * 32 + hi16) ^ asw));
                    bf16x8 bq = *(const bf16x8*)(qcb + qrow * 256 + ((s * 32 + hi16) ^ qsw));
                    sacc = __builtin_amdgcn_mfma_f32_32x32x16_bf16(a, bq, sacc, 0, 0, 0);
                }
                __builtin_amdgcn_s_setprio(0);
            }

            __builtin_amdgcn_s_barrier();   // softmax entry: buf1 (K5) dead -> P/stats overlay

            // ---- pass 1: lane-local masked max ----
            const int kbase_ = kb * 128 + g * 32 + 4 * hi;
            float mloc = NEGINF;
#pragma unroll
            for (int r = 0; r < 16; r++) {
                int kg = kbase_ + (r & 3) + 8 * (r >> 2);
                float v = (kg > qg) ? NEGINF : sacc[r];
                mloc = fmaxf(mloc, v);
            }
            mloc = fmaxf(mloc, __shfl_xor(mloc, 32));
            if (hi == 0) pmax_s[qrow * 4 + g] = mloc;
            BARL;

            // ---- pass 2: m_new, exp, P write, partial sums ----
            float4 pm = *(const float4*)&pmax_s[qrow * 4];
            float m_new = fmaxf(fmaxf(fmaxf(pm.x, pm.y), fmaxf(pm.z, pm.w)), m_r);
            float rv = __expf(m_r - m_new);
            float ps = 0.f; uint w[8];
#pragma unroll
            for (int j = 0; j < 8; j++) {
                int kg0 = kbase_ + ((2 * j) & 3) + 8 * ((2 * j) >> 2);
                int kg1 = kbase_ + ((2 * j + 1) & 3) + 8 * ((2 * j + 1) >> 2);
                float e0 = (kg0 > qg) ? 0.f : __expf(sacc[2 * j] - m_new);
                float e1 = (kg1 > qg) ? 0.f : __expf(sacc[2 * j + 1] - m_new);
                ps += e0 + e1;
                w[j] = (uint)f2bf(e0) | ((uint)f2bf(e1) << 16);
            }
            ps += __shfl_xor(ps, 32);
            if (hi == 0) psum_s[qrow * 4 + g] = ps;
            if (g == 0 && hi == 0) stat_s[qrow] = rv;      // rv identical across g-waves
#pragma unroll
            for (int j = 0; j < 4; j++) {
                uint2 pw; pw.x = w[2 * j]; pw.y = w[2 * j + 1];
                *(uint2*)(Pb + qrow * 256 + ((g * 64 + j * 16 + hi * 8) ^ qsw)) = pw;
            }
            BARL;

            // ---- finish stats; rescale O; hoist P fragments ----
            float4 ps4 = *(const float4*)&psum_s[qrow * 4];
            l_r = l_r * rv + (ps4.x + ps4.y + ps4.z + ps4.w);
            m_r = m_new;
            float rs[16];
#pragma unroll
            for (int r = 0; r < 16; r++)
                rs[r] = stat_s[qh * 32 + (r & 3) + 8 * (r >> 2) + 4 * hi];
#pragma unroll
            for (int c = 0; c < 6; c++)
#pragma unroll
                for (int r = 0; r < 16; r++) oacc[c][r] *= rs[r];
            bf16x8 pa[8];
#pragma unroll
            for (int s = 0; s < 8; s++)
                pa[s] = *(const bf16x8*)(Pb + qrow * 256 + ((s * 32 + hi16) ^ qsw));

            // ---- PV: 6 dd-chunk phases ----
#pragma unroll
            for (int c = 0; c < 6; c++) {
                PHASE_SYNC;                                // V chunk c landed; P/stats consumed (c==0)
                if (c < 5) {
#pragma unroll
                    for (int r = 0; r < 4; r++)
                        gload16(vc + (size_t)(c + 1) * 524288 + (size_t)r * 131072,
                                pool + ((c + 1) & 1) * 32768 + r * 8192 + wid * 1024);
                } else if (kb + 1 < nkb) {
#pragma unroll
                    for (int r = 0; r < 4; r++)            // next-iter K0 -> buf0
                        gload16(kc + 196608 + (size_t)r * 49152, pool + r * 8192 + wid * 1024);
                }
                const char* vbuf = pool + (c & 1) * 32768;
                __builtin_amdgcn_s_setprio(1);
#pragma unroll
                for (int s = 0; s < 8; s++) {
                    bf16x8 bv = *(const bf16x8*)(vbuf + arow * 256 + ((s * 32 + hi16) ^ asw));
                    oacc[c] = __builtin_amdgcn_mfma_f32_32x32x16_bf16(pa[s], bv, oacc[c], 0, 0, 0);
                }
                __builtin_amdgcn_s_setprio(0);
            }
        }

        // ---- epilogue: exchange l, divide, write per-head output over Qr rows ----
        asm volatile("s_waitcnt vmcnt(0) lgkmcnt(0)" ::: "memory");
        __builtin_amdgcn_s_barrier();
        if (g == 0 && hi == 0) stat_s[qrow] = l_r;
        BARL;
        float inv16[16];
#pragma unroll
        for (int r = 0; r < 16; r++)
            inv16[r] = 1.0f / stat_s[qh * 32 + (r & 3) + 8 * (r >> 2) + 4 * hi];
        BARL;                                              // stats consumed; safe for next tile
        ushort* obase = Oh + ((size_t)(bh * 2048 + q0 + qh * 32)) * 768;
#pragma unroll
        for (int c = 0; c < 6; c++) {
            int dd = c * 128 + g * 32 + l31;
#pragma unroll
            for (int r = 0; r < 16; r++) {
                int rq = (r & 3) + 8 * (r >> 2) + 4 * hi;
                obase[(size_t)rq * 768 + dd] = f2bf(oacc[c][r] * inv16[r]);
            }
        }
    }
}

// ---------------- head-sum reduce: out[b][t][d] = sum_h Oh[b][h][t][d] ----------------
__global__ void k_reduce(const ushort* __restrict__ Oh, float* __restrict__ out) {
    int i = blockIdx.x * blockDim.x + threadIdx.x;
    if (i >= 786432) return;                 // 2*2048*768/4
    size_t base = (size_t)i * 4;
    int b = (base >= 1572864) ? 1 : 0;       // 2048*768 = 1572864
    size_t rem = base - (size_t)b * 1572864;
    const ushort* src = Oh + (size_t)b * 8 * 1572864 + rem;
    float4 acc = {0.f, 0.f, 0.f, 0.f};
#pragma unroll
    for (int h = 0; h < 8; h++) {
        ushort4 v = *(const ushort4*)(src + (size_t)h * 1572864);
        acc.x += bf2f(v.x); acc.y += bf2f(v.y); acc.z += bf2f(v.z); acc.w += bf2f(v.w);
    }
    *(float4*)&out[base] = acc;
}

extern "C" void kernel_launch(void* const* d_in, const int* in_sizes, int n_in,
                              void* d_out, int out_size, void* d_ws, size_t ws_size,
                              hipStream_t stream) {
    const float* x = (const float*)d_in[0];
    const float* M = (const float*)d_in[1];
    const float* V = (const float*)d_in[2];
    const int* pos = (const int*)d_in[3];
    float* out = (float*)d_out;
    char* ws = (char*)d_ws;

    // workspace layout (bytes)
    ushort* xb   = (ushort*)(ws);                 //  6,291,456  x bf16 [4096][768]
    ushort* Mt   = (ushort*)(ws + 6291456);       //  9,437,184  M^T bf16 [6144][768]
    ushort* Vt   = (ushort*)(ws + 15728640);      //  9,437,184  V^T bf16 [6144][768]
    ushort* Qr   = (ushort*)(ws + 25165824);      // 50,331,648  Q bf16 [b][h][t][768] (later Oh)
    ushort* valT = (ushort*)(ws + 75497472);      // 50,331,648  val^T bf16 [b][h][dd][t]
    ushort* Kr   = (ushort*)(ws + 125829120);     //  6,291,456  K bf16 [b][t][768]

    k_convx<<<3072, 256, 0, stream>>>(x, xb, 786432);
    k_tconv<<<dim3(24, 192), 256, 0, stream>>>(M, Mt, 768, 6144);
    k_tconv<<<dim3(24, 192), 256, 0, stream>>>(V, Vt, 768, 6144);
    k_gemm<0><<<dim3(32, 48), 256, 0, stream>>>(xb, Mt, Qr);
    k_gemm<1><<<dim3(48, 32), 256, 0, stream>>>(Vt, xb, valT);
    k_ropeq<<<12288, 256, 0, stream>>>(Qr, pos, 32768);
    k_ropek<<<1536, 256, 0, stream>>>(x, Kr, pos, 4096);
    k_attn<<<dim3(16, 8, 2), 512, 0, stream>>>(Qr, Kr, valT, Qr /*Oh overwrites Qr*/);
    k_reduce<<<3072, 256, 0, stream>>>(Qr, out);
}

// Round 5
// 371.359 us; speedup vs baseline: 3.2992x; 1.0006x over previous
//
#include <hip/hip_runtime.h>
#include <hip/hip_bf16.h>

typedef __bf16 bf16x8 __attribute__((ext_vector_type(8)));
typedef float f32x4 __attribute__((ext_vector_type(4)));
typedef float f32x16 __attribute__((ext_vector_type(16)));

// B=2, T=2048, d=768, h=8
#define SCALE 0.03608439182435161f   // 1/sqrt(768)
#define NEGINF (-1e30f)

static __device__ __forceinline__ ushort f2bf(float f) {
    union { float f; unsigned u; } v; v.f = f;
    unsigned r = (v.u + 0x7fff + ((v.u >> 16) & 1)) >> 16;  // RTE
    return (ushort)r;
}
static __device__ __forceinline__ float bf2f(ushort u) {
    union { unsigned u; float f; } v; v.u = ((unsigned)u) << 16;
    return v.f;
}

// async 16B global -> LDS (dest: wave-uniform base + lane*16)
static __device__ __forceinline__ void gload16(const void* g, void* lds) {
    __builtin_amdgcn_global_load_lds((const __attribute__((address_space(1))) void*)g,
                                     (__attribute__((address_space(3))) void*)lds, 16, 0, 0);
}

#define WAITVM4 asm volatile("s_waitcnt vmcnt(4)" ::: "memory")
#define WAITVM0 asm volatile("s_waitcnt vmcnt(0)" ::: "memory")
#define BARX __builtin_amdgcn_s_barrier()
#define PHASE_SYNC do { asm volatile("s_waitcnt vmcnt(0) lgkmcnt(0)" ::: "memory"); \
                        __builtin_amdgcn_s_barrier(); \
                        asm volatile("" ::: "memory"); } while (0)
#define BARL do { asm volatile("s_waitcnt lgkmcnt(0)" ::: "memory"); \
                  __builtin_amdgcn_s_barrier(); \
                  asm volatile("" ::: "memory"); } while (0)

// ---------------- f32 -> bf16 convert (x) ----------------
__global__ void k_convx(const float* __restrict__ x, ushort* __restrict__ xb, int n4) {
    int i = blockIdx.x * blockDim.x + threadIdx.x;
    if (i >= n4) return;
    float4 v = ((const float4*)x)[i];
    ushort4 o; o.x = f2bf(v.x); o.y = f2bf(v.y); o.z = f2bf(v.z); o.w = f2bf(v.w);
    ((ushort4*)xb)[i] = o;
}

// ---------------- f32 [R][C] -> bf16 [C][R] transpose-convert ----------------
__global__ void k_tconv(const float* __restrict__ in, ushort* __restrict__ out, int R, int C) {
    __shared__ float ts[32][33];
    int r0 = blockIdx.x * 32, c0 = blockIdx.y * 32;
    int lr = threadIdx.x >> 5, lc = threadIdx.x & 31;
#pragma unroll
    for (int i = 0; i < 4; i++) ts[lr + i * 8][lc] = in[(r0 + lr + i * 8) * C + c0 + lc];
    __syncthreads();
#pragma unroll
    for (int i = 0; i < 4; i++) out[(c0 + lr + i * 8) * R + r0 + lc] = f2bf(ts[lc][lr + i * 8]);
}

// ---------------- bf16 GEMM: C[M][N] = A[M][768] * Bt[N][768]^T ----------------
template <int EPI>
__global__ __launch_bounds__(256) void k_gemm(const ushort* __restrict__ A,
                                              const ushort* __restrict__ Bt,
                                              ushort* __restrict__ out) {
    __shared__ ushort As[128 * 40];
    __shared__ ushort Bs[128 * 40];
    const int m0 = blockIdx.x * 128, n0 = blockIdx.y * 128;
    const int tid = threadIdx.x, lane = tid & 63, wid = tid >> 6;
    const int wm = (wid >> 1) * 64, wn = (wid & 1) * 64;
    f32x4 acc[4][4] = {};

    for (int kt = 0; kt < 768; kt += 32) {
#pragma unroll
        for (int i = 0; i < 2; i++) {
            int c = tid + i * 256;
            int row = c >> 2, kc = (c & 3) * 8;
            uint4 va = *(const uint4*)&A[(m0 + row) * 768 + kt + kc];
            *(uint4*)&As[row * 40 + kc] = va;
            uint4 vb = *(const uint4*)&Bt[(n0 + row) * 768 + kt + kc];
            *(uint4*)&Bs[row * 40 + kc] = vb;
        }
        __syncthreads();
        bf16x8 af[4], bfr[4];
#pragma unroll
        for (int m = 0; m < 4; m++)
            af[m] = *(const bf16x8*)&As[(wm + m * 16 + (lane & 15)) * 40 + (lane >> 4) * 8];
#pragma unroll
        for (int n = 0; n < 4; n++)
            bfr[n] = *(const bf16x8*)&Bs[(wn + n * 16 + (lane & 15)) * 40 + (lane >> 4) * 8];
#pragma unroll
        for (int m = 0; m < 4; m++)
#pragma unroll
            for (int n = 0; n < 4; n++)
                acc[m][n] = __builtin_amdgcn_mfma_f32_16x16x32_bf16(af[m], bfr[n], acc[m][n], 0, 0, 0);
        __syncthreads();
    }

#pragma unroll
    for (int m = 0; m < 4; m++) {
#pragma unroll
        for (int n = 0; n < 4; n++) {
#pragma unroll
            for (int r = 0; r < 4; r++) {
                int row = m0 + wm + m * 16 + (lane >> 4) * 4 + r;
                int col = n0 + wn + n * 16 + (lane & 15);
                float v = acc[m][n][r];
                int idx;
                if (EPI == 0) {
                    int b = row >> 11, t = row & 2047;
                    int hh = col / 768, dd = col - hh * 768;
                    idx = ((b * 8 + hh) * 2048 + t) * 768 + dd;
                } else {
                    int hh = row / 768, dd = row - hh * 768;
                    int b = col >> 11, t = col & 2047;
                    idx = ((b * 8 + hh) * 768 + dd) * 2048 + t;
                }
                out[idx] = f2bf(v);
            }
        }
    }
}

// ---------------- RoPE on Q in-place (bf16, layout [b][h][t][768]); folds SCALE ----------------
__global__ void k_ropeq(ushort* __restrict__ Q, const int* __restrict__ pos, int nrows) {
    int i = blockIdx.x * blockDim.x + threadIdx.x;
    int row = i / 96, j4 = (i % 96) * 4;
    if (row >= nrows) return;
    float p = (float)pos[row & 2047];
    ushort4 u1 = *(ushort4*)&Q[row * 768 + j4];
    ushort4 u2 = *(ushort4*)&Q[row * 768 + 384 + j4];
    ushort4 o1, o2;
#pragma unroll
    for (int k = 0; k < 4; k++) {
        float inv = exp2f(-(float)(j4 + k) * (13.287712379549449f / 384.0f));
        float ang = p * inv;
        float s, c; sincosf(ang, &s, &c);
        float x1 = bf2f(((ushort*)&u1)[k]), x2 = bf2f(((ushort*)&u2)[k]);
        ((ushort*)&o1)[k] = f2bf((x1 * c - x2 * s) * SCALE);
        ((ushort*)&o2)[k] = f2bf((x1 * s + x2 * c) * SCALE);
    }
    *(ushort4*)&Q[row * 768 + j4] = o1;
    *(ushort4*)&Q[row * 768 + 384 + j4] = o2;
}

// ---------------- RoPE(x) -> Kr bf16 (layout [b][t][768]) ----------------
__global__ void k_ropek(const float* __restrict__ x, ushort* __restrict__ Kr,
                        const int* __restrict__ pos, int nrows) {
    int i = blockIdx.x * blockDim.x + threadIdx.x;
    int row = i / 96, j4 = (i % 96) * 4;
    if (row >= nrows) return;
    float p = (float)pos[row & 2047];
    float4 x1 = *(const float4*)&x[row * 768 + j4];
    float4 x2 = *(const float4*)&x[row * 768 + 384 + j4];
    ushort4 o1, o2;
    float a1[4] = {x1.x, x1.y, x1.z, x1.w};
    float a2[4] = {x2.x, x2.y, x2.z, x2.w};
#pragma unroll
    for (int k = 0; k < 4; k++) {
        float inv = exp2f(-(float)(j4 + k) * (13.287712379549449f / 384.0f));
        float ang = p * inv;
        float s, c; sincosf(ang, &s, &c);
        ((ushort*)&o1)[k] = f2bf(a1[k] * c - a2[k] * s);
        ((ushort*)&o2)[k] = f2bf(a1[k] * s + a2[k] * c);
    }
    *(ushort4*)&Kr[row * 768 + j4] = o1;
    *(ushort4*)&Kr[row * 768 + 384 + j4] = o2;
}

// ---------------- Flash attention v5: counted-vmcnt end-issue pipeline ----------------
// QBLK=64, KBLK=128, 512 threads (8 waves), 1 block/CU. Same geometry as v4,
// but phases are {s_waitcnt vmcnt(4); barrier; compute chunk c; barrier;
// issue chunk c+2}. The awaited chunk always has ~2 phases of flight; loads
// never drain to 0 in the main loop (T4). V1's issue is delayed past the
// softmax so P(16KB)+stats(2.5KB) can overlay the dead slot1 (K5's buffer).
__global__ __launch_bounds__(512, 2) void k_attn(const ushort* Qr, const ushort* __restrict__ Kr,
                                                 const ushort* __restrict__ valT, ushort* Oh) {
    __shared__ alignas(128) char Qs[98304];     // [6][64 q][128 d] bf16, 16-deep XOR swizzle
    __shared__ alignas(128) char pool[65536];   // 2 x 32KB stream slots

    const int p = blockIdx.x, hh = blockIdx.y, b = blockIdx.z;
    const int bh = b * 8 + hh;
    const int tid = threadIdx.x, lane = tid & 63, wid = tid >> 6;
    const int g = wid & 3, qh = wid >> 2;       // k-tile / q-half roles
    const int l31 = lane & 31, hi = lane >> 5;
    const int hi16 = hi << 4;

    // staging geometry: chunk = [128 rows][256B], dest linear = tid*16 per 8KB round
    const int row0 = tid >> 4, col16 = tid & 15;
    const int swz = (col16 << 4) ^ ((row0 & 15) << 4);   // pre-swizzled source column

    const int arow = g * 32 + l31;              // K row (QK A) / V dd-row (PV B)
    const int qrow = qh * 32 + l31;             // Q row (QK B) / lane's q
    const int asw = (arow & 15) << 4;
    const int qsw = (qrow & 15) << 4;

    char* Pb = pool + 32768;                    // P [64 q][128 k] bf16 (slot1 overlay)
    float* pmax_s = (float*)(pool + 49152);     // [64][4]
    float* psum_s = (float*)(pool + 50176);     // [64][4]
    float* stat_s = (float*)(pool + 51200);     // [64] resc / l

    const char* Kb0 = (const char*)Kr + ((size_t)(b * 2048 + row0)) * 1536 + swz;
    const char* Vb0 = (const char*)valT + ((size_t)(bh * 768 + row0)) * 4096 + swz;

    for (int ti = 0; ti < 2; ti++) {
        const int qt = ti ? (31 - p) : p;
        const int q0 = qt * 64;
        const int nkb = (qt + 2) >> 1;
        const int qg = q0 + qrow;

        // prologue: issue Q (6 chunks, 12 rounds) + K0 -> slot0 + K1 -> slot1
        const char* qsrc = (const char*)Qr + ((size_t)(bh * 2048 + q0 + row0)) * 1536 + swz;
#pragma unroll
        for (int r = 0; r < 12; r++)
            gload16(qsrc + (r >> 1) * 256 + (size_t)(r & 1) * 49152,
                    Qs + (r >> 1) * 16384 + (r & 1) * 8192 + wid * 1024);
#pragma unroll
        for (int r = 0; r < 4; r++)
            gload16(Kb0 + (size_t)r * 49152, pool + r * 8192 + wid * 1024);
#pragma unroll
        for (int r = 0; r < 4; r++)
            gload16(Kb0 + 256 + (size_t)r * 49152, pool + 32768 + r * 8192 + wid * 1024);

        float m_r = NEGINF, l_r = 0.f;
        f32x16 oacc[6] = {};

        for (int kb = 0; kb < nkb; kb++) {
            const char* kc = Kb0 + (size_t)kb * 196608;   // +kb*128 k-rows
            const char* vc = Vb0 + (size_t)kb * 256;      // +kb*128 k-cols (bytes)
            const bool nx = (kb + 1 < nkb);

            // ---- QK^T: 6 d-chunk phases ----
            f32x16 sacc = {};
#pragma unroll
            for (int c = 0; c < 6; c++) {
                WAITVM4; BARX;                            // chunk c landed; c+1 in flight
                const char* kbuf = pool + (c & 1) * 32768;
                const char* qcb = Qs + c * 16384;
                __builtin_amdgcn_s_setprio(1);
#pragma unroll
                for (int s = 0; s < 8; s++) {
                    bf16x8 a = *(const bf16x8*)(kbuf + arow * 256 + ((s * 32 + hi16) ^ asw));
                    bf16x8 bq = *(const bf16x8*)(qcb + qrow * 256 + ((s * 32 + hi16) ^ qsw));
                    sacc = __builtin_amdgcn_mfma_f32_32x32x16_bf16(a, bq, sacc, 0, 0, 0);
                }
                __builtin_amdgcn_s_setprio(0);
                BARX;                                     // slot c&1 free for overwrite
                if (c < 4) {
#pragma unroll
                    for (int r = 0; r < 4; r++)           // K_{c+2} -> slot c&1
                        gload16(kc + (c + 2) * 256 + (size_t)r * 49152,
                                pool + (c & 1) * 32768 + r * 8192 + wid * 1024);
                } else if (c == 4) {
#pragma unroll
                    for (int r = 0; r < 4; r++)           // V0 -> slot0
                        gload16(vc + (size_t)r * 131072, pool + r * 8192 + wid * 1024);
                }
                // c == 5: no issue (V1 delayed; slot1 freed for P/stats overlay)
            }

            // ---- pass 1: lane-local masked max ----
            const int kbase_ = kb * 128 + g * 32 + 4 * hi;
            float mloc = NEGINF;
#pragma unroll
            for (int r = 0; r < 16; r++) {
                int kg = kbase_ + (r & 3) + 8 * (r >> 2);
                float v = (kg > qg) ? NEGINF : sacc[r];
                mloc = fmaxf(mloc, v);
            }
            mloc = fmaxf(mloc, __shfl_xor(mloc, 32));
            if (hi == 0) pmax_s[qrow * 4 + g] = mloc;
            BARL;

            // ---- pass 2: m_new, exp, P write, partial sums ----
            float4 pm = *(const float4*)&pmax_s[qrow * 4];
            float m_new = fmaxf(fmaxf(fmaxf(pm.x, pm.y), fmaxf(pm.z, pm.w)), m_r);
            float rv = __expf(m_r - m_new);
            float ps = 0.f; uint w[8];
#pragma unroll
            for (int j = 0; j < 8; j++) {
                int kg0 = kbase_ + ((2 * j) & 3) + 8 * ((2 * j) >> 2);
                int kg1 = kbase_ + ((2 * j + 1) & 3) + 8 * ((2 * j + 1) >> 2);
                float e0 = (kg0 > qg) ? 0.f : __expf(sacc[2 * j] - m_new);
                float e1 = (kg1 > qg) ? 0.f : __expf(sacc[2 * j + 1] - m_new);
                ps += e0 + e1;
                w[j] = (uint)f2bf(e0) | ((uint)f2bf(e1) << 16);
            }
            ps += __shfl_xor(ps, 32);
            if (hi == 0) psum_s[qrow * 4 + g] = ps;
            if (g == 0 && hi == 0) stat_s[qrow] = rv;      // rv identical across g-waves
#pragma unroll
            for (int j = 0; j < 4; j++) {
                uint2 pw; pw.x = w[2 * j]; pw.y = w[2 * j + 1];
                *(uint2*)(Pb + qrow * 256 + ((g * 64 + j * 16 + hi * 8) ^ qsw)) = pw;
            }
            BARL;

            // ---- pass 3: finish stats; rescale O; hoist P fragments ----
            float4 ps4 = *(const float4*)&psum_s[qrow * 4];
            l_r = l_r * rv + (ps4.x + ps4.y + ps4.z + ps4.w);
            m_r = m_new;
            float rs[16];
#pragma unroll
            for (int r = 0; r < 16; r++)
                rs[r] = stat_s[qh * 32 + (r & 3) + 8 * (r >> 2) + 4 * hi];
#pragma unroll
            for (int c = 0; c < 6; c++)
#pragma unroll
                for (int r = 0; r < 16; r++) oacc[c][r] *= rs[r];
            bf16x8 pa[8];
#pragma unroll
            for (int s = 0; s < 8; s++)
                pa[s] = *(const bf16x8*)(Pb + qrow * 256 + ((s * 32 + hi16) ^ qsw));

            // ---- PV: 6 dd-chunk phases ----
#pragma unroll
            for (int c = 0; c < 6; c++) {
                if (c == 0) {
                    PHASE_SYNC;                            // V0 landed; P/stats reads drained
#pragma unroll
                    for (int r = 0; r < 4; r++)            // V1 -> slot1 (over P/stats)
                        gload16(vc + 524288 + (size_t)r * 131072,
                                pool + 32768 + r * 8192 + wid * 1024);
                } else if (c < 5 || nx) {
                    WAITVM4; BARX;                         // V_c landed; V_{c+1} in flight
                } else {
                    WAITVM0; BARX;                         // last iter tail: only V5 out
                }
                const char* vbuf = pool + (c & 1) * 32768;
                __builtin_amdgcn_s_setprio(1);
#pragma unroll
                for (int s = 0; s < 8; s++) {
                    bf16x8 bv = *(const bf16x8*)(vbuf + arow * 256 + ((s * 32 + hi16) ^ asw));
                    oacc[c] = __builtin_amdgcn_mfma_f32_32x32x16_bf16(pa[s], bv, oacc[c], 0, 0, 0);
                }
                __builtin_amdgcn_s_setprio(0);
                BARX;                                      // slot c&1 free
                if (c == 0) {
#pragma unroll
                    for (int r = 0; r < 4; r++)            // V2 -> slot0
                        gload16(vc + 2 * 524288 + (size_t)r * 131072,
                                pool + r * 8192 + wid * 1024);
                } else if (c < 4) {
#pragma unroll
                    for (int r = 0; r < 4; r++)            // V_{c+2} -> slot c&1
                        gload16(vc + (size_t)(c + 2) * 524288 + (size_t)r * 131072,
                                pool + (c & 1) * 32768 + r * 8192 + wid * 1024);
                } else if (c == 4 && nx) {
#pragma unroll
                    for (int r = 0; r < 4; r++)            // next-iter K0 -> slot0
                        gload16(kc + 196608 + (size_t)r * 49152, pool + r * 8192 + wid * 1024);
                } else if (c == 5 && nx) {
#pragma unroll
                    for (int r = 0; r < 4; r++)            // next-iter K1 -> slot1
                        gload16(kc + 196608 + 256 + (size_t)r * 49152,
                                pool + 32768 + r * 8192 + wid * 1024);
                }
            }
        }

        // ---- epilogue: exchange l, divide, write per-head output over Qr rows ----
        if (g == 0 && hi == 0) stat_s[qrow] = l_r;
        BARL;
        float inv16[16];
#pragma unroll
        for (int r = 0; r < 16; r++)
            inv16[r] = 1.0f / stat_s[qh * 32 + (r & 3) + 8 * (r >> 2) + 4 * hi];
        BARL;                                              // stats consumed; safe for next tile
        ushort* obase = Oh + ((size_t)(bh * 2048 + q0 + qh * 32)) * 768;
#pragma unroll
        for (int c = 0; c < 6; c++) {
            int dd = c * 128 + g * 32 + l31;
#pragma unroll
            for (int r = 0; r < 16; r++) {
                int rq = (r & 3) + 8 * (r >> 2) + 4 * hi;
                obase[(size_t)rq * 768 + dd] = f2bf(oacc[c][r] * inv16[r]);
            }
        }
    }
}

// ---------------- head-sum reduce: out[b][t][d] = sum_h Oh[b][h][t][d] ----------------
__global__ void k_reduce(const ushort* __restrict__ Oh, float* __restrict__ out) {
    int i = blockIdx.x * blockDim.x + threadIdx.x;
    if (i >= 786432) return;                 // 2*2048*768/4
    size_t base = (size_t)i * 4;
    int b = (base >= 1572864) ? 1 : 0;       // 2048*768 = 1572864
    size_t rem = base - (size_t)b * 1572864;
    const ushort* src = Oh + (size_t)b * 8 * 1572864 + rem;
    float4 acc = {0.f, 0.f, 0.f, 0.f};
#pragma unroll
    for (int h = 0; h < 8; h++) {
        ushort4 v = *(const ushort4*)(src + (size_t)h * 1572864);
        acc.x += bf2f(v.x); acc.y += bf2f(v.y); acc.z += bf2f(v.z); acc.w += bf2f(v.w);
    }
    *(float4*)&out[base] = acc;
}

extern "C" void kernel_launch(void* const* d_in, const int* in_sizes, int n_in,
                              void* d_out, int out_size, void* d_ws, size_t ws_size,
                              hipStream_t stream) {
    const float* x = (const float*)d_in[0];
    const float* M = (const float*)d_in[1];
    const float* V = (const float*)d_in[2];
    const int* pos = (const int*)d_in[3];
    float* out = (float*)d_out;
    char* ws = (char*)d_ws;

    // workspace layout (bytes)
    ushort* xb   = (ushort*)(ws);                 //  6,291,456  x bf16 [4096][768]
    ushort* Mt   = (ushort*)(ws + 6291456);       //  9,437,184  M^T bf16 [6144][768]
    ushort* Vt   = (ushort*)(ws + 15728640);      //  9,437,184  V^T bf16 [6144][768]
    ushort* Qr   = (ushort*)(ws + 25165824);      // 50,331,648  Q bf16 [b][h][t][768] (later Oh)
    ushort* valT = (ushort*)(ws + 75497472);      // 50,331,648  val^T bf16 [b][h][dd][t]
    ushort* Kr   = (ushort*)(ws + 125829120);     //  6,291,456  K bf16 [b][t][768]

    k_convx<<<3072, 256, 0, stream>>>(x, xb, 786432);
    k_tconv<<<dim3(24, 192), 256, 0, stream>>>(M, Mt, 768, 6144);
    k_tconv<<<dim3(24, 192), 256, 0, stream>>>(V, Vt, 768, 6144);
    k_gemm<0><<<dim3(32, 48), 256, 0, stream>>>(xb, Mt, Qr);
    k_gemm<1><<<dim3(48, 32), 256, 0, stream>>>(Vt, xb, valT);
    k_ropeq<<<12288, 256, 0, stream>>>(Qr, pos, 32768);
    k_ropek<<<1536, 256, 0, stream>>>(x, Kr, pos, 4096);
    k_attn<<<dim3(16, 8, 2), 512, 0, stream>>>(Qr, Kr, valT, Qr /*Oh overwrites Qr*/);
    k_reduce<<<3072, 256, 0, stream>>>(Qr, out);
}